// Round 16
// baseline (649.147 us; speedup 1.0000x reference)
//
#include <hip/hip_runtime.h>

typedef unsigned char u8;
typedef unsigned short u16;
typedef unsigned int u32;
typedef unsigned long long u64;
typedef __attribute__((ext_vector_type(8))) short s16x8;   // 8 bf16 = 4 VGPR
typedef __attribute__((ext_vector_type(4))) float f32x4;   // MFMA acc

#define T_DIM 64
#define B_DIM 8
#define N_DIM 64
#define D_DIM 384
#define H_DIM 8
#define HD 48
#define M_ROWS 32768
#define CH 196608

// W split-image geometry: per W: [ntile 3][kstep 12][split 2][kc 4][n 128][ki 8] bf16
#define IMG_PER_KSTEP 16384            // 1024 chunks * 16B
#define IMG_PER_NTILE (12 * IMG_PER_KSTEP)
#define IMG_PER_W (3 * IMG_PER_NTILE)  // 589824 B

union I4S { int4 i; s16x8 v; };

// ---------------------------------------------------------------------------
// Exact bf16 truncation split helpers
// ---------------------------------------------------------------------------
__device__ __forceinline__ void split8(const float* e, int4& o1, int4& o2, int4& o3) {
  u16 h1[8], h2[8], h3[8];
#pragma unroll
  for (int i = 0; i < 8; ++i) {
    const float x = e[i];
    const u32 b = __float_as_uint(x);
    h1[i] = (u16)(b >> 16);
    const float x1 = __uint_as_float(b & 0xFFFF0000u);
    const float r1 = x - x1;
    const u32 c = __float_as_uint(r1);
    h2[i] = (u16)(c >> 16);
    const float x2 = __uint_as_float(c & 0xFFFF0000u);
    const float r2 = r1 - x2;
    h3[i] = (u16)(__float_as_uint(r2) >> 16);
  }
  o1 = make_int4((int)((u32)h1[0] | ((u32)h1[1] << 16)), (int)((u32)h1[2] | ((u32)h1[3] << 16)),
                 (int)((u32)h1[4] | ((u32)h1[5] << 16)), (int)((u32)h1[6] | ((u32)h1[7] << 16)));
  o2 = make_int4((int)((u32)h2[0] | ((u32)h2[1] << 16)), (int)((u32)h2[2] | ((u32)h2[3] << 16)),
                 (int)((u32)h2[4] | ((u32)h2[5] << 16)), (int)((u32)h2[6] | ((u32)h2[7] << 16)));
  o3 = make_int4((int)((u32)h3[0] | ((u32)h3[1] << 16)), (int)((u32)h3[2] | ((u32)h3[3] << 16)),
                 (int)((u32)h3[4] | ((u32)h3[5] << 16)), (int)((u32)h3[6] | ((u32)h3[7] << 16)));
}

// 2-way split only (A-side)
__device__ __forceinline__ void split8_2(const float* e, int4& o1, int4& o2) {
  u16 h1[8], h2[8];
#pragma unroll
  for (int i = 0; i < 8; ++i) {
    const float x = e[i];
    const u32 b = __float_as_uint(x);
    h1[i] = (u16)(b >> 16);
    const float x1 = __uint_as_float(b & 0xFFFF0000u);
    const float r1 = x - x1;
    h2[i] = (u16)(__float_as_uint(r1) >> 16);
  }
  o1 = make_int4((int)((u32)h1[0] | ((u32)h1[1] << 16)), (int)((u32)h1[2] | ((u32)h1[3] << 16)),
                 (int)((u32)h1[4] | ((u32)h1[5] << 16)), (int)((u32)h1[6] | ((u32)h1[7] << 16)));
  o2 = make_int4((int)((u32)h2[0] | ((u32)h2[1] << 16)), (int)((u32)h2[2] | ((u32)h2[3] << 16)),
                 (int)((u32)h2[4] | ((u32)h2[5] << 16)), (int)((u32)h2[6] | ((u32)h2[7] << 16)));
}

__device__ __forceinline__ void split1(float xx, u16& a, u16& b2, u16& c) {
  const u32 u = __float_as_uint(xx);
  a = (u16)(u >> 16);
  const float x1 = __uint_as_float(u & 0xFFFF0000u);
  const float r1 = xx - x1;
  const u32 u2 = __float_as_uint(r1);
  b2 = (u16)(u2 >> 16);
  const float x2 = __uint_as_float(u2 & 0xFFFF0000u);
  const float r2 = r1 - x2;
  c = (u16)(__float_as_uint(r2) >> 16);
}

__device__ __forceinline__ u64 packmask48(const u8* p) {
  const int4 r0 = ((const int4*)p)[0];
  const int4 r1 = ((const int4*)p)[1];
  const int4 r2 = ((const int4*)p)[2];
  u32 wv[12] = {(u32)r0.x, (u32)r0.y, (u32)r0.z, (u32)r0.w,
                (u32)r1.x, (u32)r1.y, (u32)r1.z, (u32)r1.w,
                (u32)r2.x, (u32)r2.y, (u32)r2.z, (u32)r2.w};
  u64 bits = 0;
#pragma unroll
  for (int w = 0; w < 12; ++w) {
    const u32 u = wv[w];
    const u32 nib = (u & 1u) | ((u >> 7) & 2u) | ((u >> 14) & 4u) | ((u >> 21) & 8u);
    bits |= (u64)nib << (w * 4);
  }
  return bits;
}

// ---------------------------------------------------------------------------
// prep_w: split weight matrices into 2-split fragment-image layout (swizzled).
// ---------------------------------------------------------------------------
__global__ __launch_bounds__(256) void prep_w(const float* __restrict__ W0,
                                              const float* __restrict__ W1,
                                              const float* __restrict__ W2,
                                              const float* __restrict__ W3,
                                              char* __restrict__ img) {
  const int widx = blockIdx.x & 3;
  const int nt = blockIdx.x >> 2;
  const float* W = (widx == 0) ? W0 : (widx == 1) ? W1 : (widx == 2) ? W2 : W3;
  char* base = img + (size_t)widx * IMG_PER_W + (size_t)nt * IMG_PER_NTILE;
  const int tid = threadIdx.x;
  const int nr = tid >> 1;
  const int kh = tid & 1;
  for (int ks = 0; ks < 12; ++ks) {
    const float* src = W + (size_t)(nt * 128 + nr) * D_DIM + ks * 32 + kh * 16;
    float4 v0 = ((const float4*)src)[0];
    float4 v1 = ((const float4*)src)[1];
    float4 v2 = ((const float4*)src)[2];
    float4 v3 = ((const float4*)src)[3];
    float e[16] = {v0.x, v0.y, v0.z, v0.w, v1.x, v1.y, v1.z, v1.w,
                   v2.x, v2.y, v2.z, v2.w, v3.x, v3.y, v3.z, v3.w};
    int4* dst = (int4*)(base + (size_t)ks * IMG_PER_KSTEP);
#pragma unroll
    for (int sub = 0; sub < 2; ++sub) {
      const int kc = kh * 2 + sub;
      int4 o1, o2, o3;
      split8(e + sub * 8, o1, o2, o3);
      dst[(0 * 4 + kc) * 128 + (nr ^ kc)] = o1;
      dst[(1 * 4 + kc) * 128 + (nr ^ kc)] = o2;
    }
  }
}

// ---------------------------------------------------------------------------
// gemm_bn2 (qkv): BM=64 x BN=128 tile, 2x2 waves (wave tile 32x64), BK=32.
// A f32 split-staged (2 planes) + B image, BOTH double-buffered in LDS
// (48 KB -> 3 blocks/CU), ONE barrier per K-step (the proven gemm_bn1
// schedule). Products per acc (bitwise order kept): (A1,B0),(A0,B1),(A0,B0).
// Grid 1536, XCD swizzle. BN-stats partials: 512 strips of 64 rows.
// ---------------------------------------------------------------------------
__global__ __launch_bounds__(256) void gemm_bn2(const float* __restrict__ A,
                                                const char* __restrict__ imgW,
                                                float* __restrict__ C,
                                                double* __restrict__ part) {
  __shared__ __align__(16) char shraw[49152];  // B[2][16KB] @0, A[2][8KB] @32768
  int4* BchW = (int4*)shraw;
  const s16x8* BchR = (const s16x8*)shraw;
  int4* AchW = (int4*)shraw + 2048;            // byte 32768
  const s16x8* AchR = (const s16x8*)shraw + 2048;

  const int tid = threadIdx.x;
  const int lane = tid & 63;
  const int w = tid >> 6;
  const int wm = w >> 1, wn = w & 1;
  const int lr = lane & 15;
  const int kcL = lane >> 4;

  // XCD swizzle: 1536 blocks; same slot -> same XCD for a strip's 3 ntiles.
  const int wgid = blockIdx.x;
  const int xcdSlot = wgid & 7;
  const int inner = wgid >> 3;          // [0,192)
  const int ntx = inner % 3;
  const int by = (inner / 3) * 8 + xcdSlot;   // [0,512)
  const int bn = ntx * 128;
  const int bm = by * 64;

  const int4* imgI = (const int4*)(imgW + (size_t)ntx * IMG_PER_NTILE);

  int axc[2], bxc[4];
#pragma unroll
  for (int f = 0; f < 2; ++f)
    axc[f] = kcL * 64 + ((wm * 32 + f * 16 + lr) ^ kcL);
#pragma unroll
  for (int f = 0; f < 4; ++f)
    bxc[f] = kcL * 128 + ((wn * 64 + f * 16 + lr) ^ kcL);

  float4 a0, a1;
  int4 b0, b1, b2, b3;
  const int arow = tid >> 2;           // 0..63
  const int akc = tid & 3;             // k-chunk 0..3 (8 elems each)

#define LOADA(ks)                                                             \
  do {                                                                        \
    const float* ap = A + (size_t)(bm + arow) * D_DIM + (ks) * 32 + akc * 8;  \
    a0 = ((const float4*)ap)[0];                                              \
    a1 = ((const float4*)ap)[1];                                              \
  } while (0)

#define LOADB(ks)                                                             \
  do {                                                                        \
    b0 = imgI[(ks) * 1024 + tid];                                             \
    b1 = imgI[(ks) * 1024 + tid + 256];                                       \
    b2 = imgI[(ks) * 1024 + tid + 512];                                       \
    b3 = imgI[(ks) * 1024 + tid + 768];                                       \
  } while (0)

#define WRITES(buf)                                                           \
  do {                                                                        \
    float e[8] = {a0.x, a0.y, a0.z, a0.w, a1.x, a1.y, a1.z, a1.w};            \
    int4 o1, o2;                                                              \
    split8_2(e, o1, o2);                                                      \
    AchW[(buf) * 512 + 0 * 256 + akc * 64 + (arow ^ akc)] = o1;               \
    AchW[(buf) * 512 + 1 * 256 + akc * 64 + (arow ^ akc)] = o2;               \
    BchW[(buf) * 1024 + tid] = b0;                                            \
    BchW[(buf) * 1024 + tid + 256] = b1;                                      \
    BchW[(buf) * 1024 + tid + 512] = b2;                                      \
    BchW[(buf) * 1024 + tid + 768] = b3;                                      \
  } while (0)

  f32x4 acc[2][4] = {};

  LOADA(0); LOADB(0);
  WRITES(0);
  __syncthreads();

  int cur = 0;
  for (int ks = 0; ks < 12; ++ks) {
    if (ks < 11) { LOADA(ks + 1); LOADB(ks + 1); }
    s16x8 af[2][2];
#pragma unroll
    for (int s = 0; s < 2; ++s)
#pragma unroll
      for (int fm = 0; fm < 2; ++fm)
        af[s][fm] = AchR[cur * 512 + s * 256 + axc[fm]];
#pragma unroll
    for (int fn = 0; fn < 4; ++fn) {
      const s16x8 bf0 = BchR[cur * 1024 + bxc[fn]];
      const s16x8 bf1 = BchR[cur * 1024 + 512 + bxc[fn]];
#pragma unroll
      for (int fm = 0; fm < 2; ++fm)
        acc[fm][fn] = __builtin_amdgcn_mfma_f32_16x16x32_bf16(af[1][fm], bf0, acc[fm][fn], 0, 0, 0);
#pragma unroll
      for (int fm = 0; fm < 2; ++fm)
        acc[fm][fn] = __builtin_amdgcn_mfma_f32_16x16x32_bf16(af[0][fm], bf1, acc[fm][fn], 0, 0, 0);
#pragma unroll
      for (int fm = 0; fm < 2; ++fm)
        acc[fm][fn] = __builtin_amdgcn_mfma_f32_16x16x32_bf16(af[0][fm], bf0, acc[fm][fn], 0, 0, 0);
    }
    if (ks < 11) {
      WRITES(cur ^ 1);
      __syncthreads();
      cur ^= 1;
    }
  }
#undef LOADA
#undef LOADB
#undef WRITES

  // C writes: row = bm + wm*32 + fm*16 + kcL*4 + r, col = bn + wn*64 + fn*16 + lr
#pragma unroll
  for (int fm = 0; fm < 2; ++fm)
#pragma unroll
    for (int fn = 0; fn < 4; ++fn) {
      const int row = bm + wm * 32 + fm * 16 + kcL * 4;
      const int col = bn + wn * 64 + fn * 16 + lr;
#pragma unroll
      for (int r = 0; r < 4; ++r)
        C[(size_t)(row + r) * D_DIM + col] = acc[fm][fn][r];
    }

  // BN partial stats over this block's 64 rows (deterministic, f64)
  __syncthreads();  // all LDS use done before reuse
  double* red = (double*)shraw;  // [rg 8][col 128][2] = 16 KB
#pragma unroll
  for (int fn = 0; fn < 4; ++fn) {
    const int col = wn * 64 + fn * 16 + lr;
    const int rg = wm * 4 + kcL;
    double s = 0.0, qd = 0.0;
#pragma unroll
    for (int fm = 0; fm < 2; ++fm)
#pragma unroll
      for (int r = 0; r < 4; ++r) {
        const double v = (double)acc[fm][fn][r];
        s += v;
        qd += v * v;
      }
    red[(rg * 128 + col) * 2 + 0] = s;
    red[(rg * 128 + col) * 2 + 1] = qd;
  }
  __syncthreads();
  if (tid < 128) {
    double S = 0.0, Q = 0.0;
#pragma unroll
    for (int rg = 0; rg < 8; ++rg) {
      S += red[(rg * 128 + tid) * 2 + 0];
      Q += red[(rg * 128 + tid) * 2 + 1];
    }
    const size_t pidx = ((size_t)by * D_DIM + bn + tid) * 2;
    part[pidx + 0] = S;
    part[pidx + 1] = Q;
  }
}

// ---------------------------------------------------------------------------
// gemm_bn1 (proj): BM=128 x BN=128; A = bf16 spikes (exact, 1 split) via LDS,
// B via LDS, BOTH double-buffered, ONE barrier per K-step (proven r13/14).
// 2 products: (A0,B1),(A0,B0). Grid 768, 256 strips of 128 rows.
// ---------------------------------------------------------------------------
__global__ __launch_bounds__(256) void gemm_bn1(const u16* __restrict__ Zb,
                                                const char* __restrict__ imgW,
                                                float* __restrict__ C,
                                                double* __restrict__ part) {
  __shared__ __align__(16) char shraw[49152];   // B[2][16384] @0, A[2][8192] @32768
  int4* BchW = (int4*)shraw;
  const s16x8* BchR = (const s16x8*)shraw;
  int4* AchW = (int4*)shraw + 2048;
  const s16x8* AchR = (const s16x8*)shraw + 2048;

  const int tid = threadIdx.x;
  const int lane = tid & 63;
  const int w = tid >> 6;
  const int wm = w >> 1, wn = w & 1;
  const int lr = lane & 15;
  const int kcL = lane >> 4;

  const int wgid = blockIdx.x;
  const int xcdSlot = wgid & 7;
  const int inner = wgid >> 3;
  const int ntx = inner % 3;
  const int by = (inner / 3) * 8 + xcdSlot;   // [0,256)
  const int bn = ntx * 128;
  const int bm = by * 128;

  const int4* imgI = (const int4*)(imgW + (size_t)ntx * IMG_PER_NTILE);

  int axc[4], bxc[4];
#pragma unroll
  for (int f = 0; f < 4; ++f) {
    axc[f] = kcL * 128 + ((wm * 64 + f * 16 + lr) ^ kcL);
    bxc[f] = kcL * 128 + ((wn * 64 + f * 16 + lr) ^ kcL);
  }

  int4 za0, za1;
  int4 b0, b1, b2, b3;
  const int c0 = tid, c1 = tid + 256;

#define LOADA1(ks)                                                            \
  do {                                                                        \
    { const int kc = c0 >> 7, mp = c0 & 127;                                  \
      za0 = *(const int4*)(Zb + (size_t)(bm + (mp ^ kc)) * D_DIM +            \
                           (ks) * 32 + kc * 8); }                             \
    { const int kc = c1 >> 7, mp = c1 & 127;                                  \
      za1 = *(const int4*)(Zb + (size_t)(bm + (mp ^ kc)) * D_DIM +            \
                           (ks) * 32 + kc * 8); }                             \
  } while (0)

#define WRITEA1(buf)                                                          \
  do {                                                                        \
    AchW[(buf) * 512 + c0] = za0;                                             \
    AchW[(buf) * 512 + c1] = za1;                                             \
  } while (0)

#define LOADB1(ks)                                                            \
  do {                                                                        \
    b0 = imgI[(ks) * 1024 + tid];                                             \
    b1 = imgI[(ks) * 1024 + tid + 256];                                       \
    b2 = imgI[(ks) * 1024 + tid + 512];                                       \
    b3 = imgI[(ks) * 1024 + tid + 768];                                       \
  } while (0)

#define WRITEB1(buf)                                                          \
  do {                                                                        \
    BchW[(buf) * 1024 + tid] = b0;                                            \
    BchW[(buf) * 1024 + tid + 256] = b1;                                      \
    BchW[(buf) * 1024 + tid + 512] = b2;                                      \
    BchW[(buf) * 1024 + tid + 768] = b3;                                      \
  } while (0)

  f32x4 acc[4][4] = {};

  LOADA1(0);
  LOADB1(0);
  WRITEA1(0);
  WRITEB1(0);
  __syncthreads();

  int cur = 0;
  for (int ks = 0; ks < 12; ++ks) {
    if (ks < 11) { LOADA1(ks + 1); LOADB1(ks + 1); }
    s16x8 af[4];
#pragma unroll
    for (int fm = 0; fm < 4; ++fm) af[fm] = AchR[cur * 512 + axc[fm]];
#pragma unroll
    for (int fn = 0; fn < 4; ++fn) {
      const s16x8 bf0 = BchR[cur * 1024 + bxc[fn]];
      const s16x8 bf1 = BchR[cur * 1024 + 512 + bxc[fn]];
#pragma unroll
      for (int fm = 0; fm < 4; ++fm)
        acc[fm][fn] = __builtin_amdgcn_mfma_f32_16x16x32_bf16(af[fm], bf1, acc[fm][fn], 0, 0, 0);
#pragma unroll
      for (int fm = 0; fm < 4; ++fm)
        acc[fm][fn] = __builtin_amdgcn_mfma_f32_16x16x32_bf16(af[fm], bf0, acc[fm][fn], 0, 0, 0);
    }
    if (ks < 11) {
      WRITEA1(cur ^ 1);
      WRITEB1(cur ^ 1);
      __syncthreads();
      cur ^= 1;
    }
  }
#undef LOADA1
#undef WRITEA1
#undef LOADB1
#undef WRITEB1

#pragma unroll
  for (int fm = 0; fm < 4; ++fm)
#pragma unroll
    for (int fn = 0; fn < 4; ++fn) {
      const int row = bm + wm * 64 + fm * 16 + kcL * 4;
      const int col = bn + wn * 64 + fn * 16 + lr;
#pragma unroll
      for (int r = 0; r < 4; ++r)
        C[(size_t)(row + r) * D_DIM + col] = acc[fm][fn][r];
    }

  __syncthreads();
  double* red = (double*)shraw;
#pragma unroll
  for (int fn = 0; fn < 4; ++fn) {
    const int col = wn * 64 + fn * 16 + lr;
    const int rg = wm * 4 + kcL;
    double s = 0.0, qd = 0.0;
#pragma unroll
    for (int fm = 0; fm < 4; ++fm)
#pragma unroll
      for (int r = 0; r < 4; ++r) {
        const double v = (double)acc[fm][fn][r];
        s += v;
        qd += v * v;
      }
    red[(rg * 128 + col) * 2 + 0] = s;
    red[(rg * 128 + col) * 2 + 1] = qd;
  }
  __syncthreads();
  if (tid < 128) {
    double S = 0.0, Q = 0.0;
#pragma unroll
    for (int rg = 0; rg < 8; ++rg) {
      S += red[(rg * 128 + tid) * 2 + 0];
      Q += red[(rg * 128 + tid) * 2 + 1];
    }
    const size_t pidx = ((size_t)by * D_DIM + bn + tid) * 2;
    part[pidx + 0] = S;
    part[pidx + 1] = Q;
  }
}

// ---------------------------------------------------------------------------
// BN stats finalize (fixed order, f64); nblk = number of row-strips in part.
// ---------------------------------------------------------------------------
__global__ void bn_stats_final(const double* __restrict__ part,
                               const float* __restrict__ gamma,
                               const float* __restrict__ beta,
                               float* __restrict__ ss, int nblk) {
  const int c = blockIdx.x * 64 + threadIdx.x;
  double s = 0.0, q = 0.0;
  for (int b = 0; b < nblk; ++b) {
    s += part[((size_t)b * D_DIM + c) * 2 + 0];
    q += part[((size_t)b * D_DIM + c) * 2 + 1];
  }
  const double n = (double)M_ROWS;
  const double mean = s / n;
  const double var = q / n - mean * mean;
  const double rstd = 1.0 / sqrt(var + 1e-5);
  const double sc = (double)gamma[c] * rstd;
  ss[c * 2 + 0] = (float)sc;
  ss[c * 2 + 1] = (float)((double)beta[c] - mean * sc);
}

// ---------------------------------------------------------------------------
// LIF scan (64 steps, stride CH). MODE 0: BN+LIF -> u8 spikes.
// MODE 2: BN+LIF in place (f32 spikes).
// ---------------------------------------------------------------------------
template <int MODE>
__global__ __launch_bounds__(256) void lif_kernel(float* Y,
                                                  const float* __restrict__ ss,
                                                  u8* __restrict__ spikes) {
  const int c = blockIdx.x * 256 + threadIdx.x;
  const int dd = c % D_DIM;
  const float scale = ss[dd * 2 + 0];
  const float shift = ss[dd * 2 + 1];
  float v = 0.0f;
  for (int t0 = 0; t0 < T_DIM; t0 += 8) {
    float xs[8];
#pragma unroll
    for (int u = 0; u < 8; ++u) xs[u] = Y[(size_t)(t0 + u) * CH + c];
#pragma unroll
    for (int u = 0; u < 8; ++u) {
      const float xv = xs[u] * scale + shift;
      const float hh = v + (xv - v) * 0.5f;
      const float sp = (hh >= 1.0f) ? 1.0f : 0.0f;
      v = (1.0f - sp) * hh;
      if (MODE == 0)
        spikes[(size_t)(t0 + u) * CH + c] = (u8)sp;
      else
        Y[(size_t)(t0 + u) * CH + c] = sp;
    }
  }
}

// ---------------------------------------------------------------------------
// Attention + fused attn_lif, MFMA version, 4 heads per 256-thread block
// (round-10..15 passing version, unchanged).
// ---------------------------------------------------------------------------
__global__ __launch_bounds__(256) void attn_kernel(const u8* __restrict__ qs,
                                                   const u8* __restrict__ ks,
                                                   const u8* __restrict__ vs,
                                                   u16* __restrict__ z) {
  const int gid = blockIdx.x;          // (x, b, head-group)
  const int hg = (gid & 1) * 4;
  const int b = (gid >> 1) & 7;
  const int x = gid >> 4;
  const int w = threadIdx.x >> 6;
  const int h = hg + w;
  const int lane = threadIdx.x & 63;

  union Slab {
    struct { u64 qm[64]; u64 km[64]; float maskT[64]; u16 vt[48][80]; } a;  // 8960 B
    float zl[64][50];                                                       // 12800 B
  };
  __shared__ Slab sh[4];  // 51200 B
  Slab& S = sh[w];

  {
    const u8* qp = qs + ((size_t)((x * B_DIM + b) * N_DIM + lane)) * D_DIM + h * HD;
    S.a.qm[lane] = packmask48(qp);
    const size_t koff = ((size_t)((lane * B_DIM + b) * N_DIM + x)) * D_DIM + h * HD;
    S.a.km[lane] = packmask48(ks + koff);
    const u8* vp = vs + koff;
    const int4 r0 = ((const int4*)vp)[0];
    const int4 r1 = ((const int4*)vp)[1];
    const int4 r2 = ((const int4*)vp)[2];
    u32 vw[12] = {(u32)r0.x, (u32)r0.y, (u32)r0.z, (u32)r0.w,
                  (u32)r1.x, (u32)r1.y, (u32)r1.z, (u32)r1.w,
                  (u32)r2.x, (u32)r2.y, (u32)r2.z, (u32)r2.w};
#pragma unroll
    for (int ww = 0; ww < 12; ++ww) {
      const u32 u = vw[ww];
#pragma unroll
      for (int e = 0; e < 4; ++e)
        S.a.vt[ww * 4 + e][lane] = ((u >> (8 * e)) & 1u) ? (u16)0x3F80 : (u16)0;
    }
    S.a.maskT[lane] = 1.0f / (float)(1 + lane);
  }
  __syncthreads();

  const int lr = lane & 15;
  const int lg = lane >> 4;
  f32x4 acc[4][3] = {};

  for (int ksi = 0; ksi < 2; ++ksi) {
    const int j0 = lg * 8 + ksi * 32;
    s16x8 bf[3];
#pragma unroll
    for (int nf = 0; nf < 3; ++nf)
      bf[nf] = *(const s16x8*)&S.a.vt[lr + nf * 16][j0];
    s16x8 af[3][4];
#pragma unroll
    for (int mf = 0; mf < 4; ++mf) {
      const int i = lr + mf * 16;
      const u64 qi = S.a.qm[i];
      union { u32 w[4]; s16x8 v; } p1, p2, p3;
#pragma unroll
      for (int pp = 0; pp < 4; ++pp) {
        u16 aa[2], bb[2], cc[2];
#pragma unroll
        for (int e = 0; e < 2; ++e) {
          const int j = j0 + pp * 2 + e;
          const int cnt = __popcll(qi & S.a.km[j]);
          int ad = i - j;
          if (ad < 0) ad = -ad;
          const float sv = (float)cnt * S.a.maskT[ad];
          split1(sv, aa[e], bb[e], cc[e]);
        }
        p1.w[pp] = (u32)aa[0] | ((u32)aa[1] << 16);
        p2.w[pp] = (u32)bb[0] | ((u32)bb[1] << 16);
        p3.w[pp] = (u32)cc[0] | ((u32)cc[1] << 16);
      }
      af[0][mf] = p1.v;
      af[1][mf] = p2.v;
      af[2][mf] = p3.v;
    }
#pragma unroll
    for (int spi = 0; spi < 3; ++spi) {
      const int sp = 2 - spi;
#pragma unroll
      for (int nf = 0; nf < 3; ++nf)
#pragma unroll
        for (int mf = 0; mf < 4; ++mf)
          acc[mf][nf] = __builtin_amdgcn_mfma_f32_16x16x32_bf16(af[sp][mf], bf[nf],
                                                                acc[mf][nf], 0, 0, 0);
    }
  }
  __syncthreads();

  const float kScale = 0.05103103630798287f;  // 384^-0.5
#pragma unroll
  for (int mf = 0; mf < 4; ++mf)
#pragma unroll
    for (int nf = 0; nf < 3; ++nf)
#pragma unroll
      for (int r = 0; r < 4; ++r)
        S.zl[mf * 16 + lg * 4 + r][lr + nf * 16] = acc[mf][nf][r] * kScale;
  __syncthreads();

  if (lane < HD) {
    float v = 0.0f;
    for (int i0 = 0; i0 < 64; i0 += 8) {
      float zv[8];
#pragma unroll
      for (int u = 0; u < 8; ++u) zv[u] = S.zl[i0 + u][lane];
#pragma unroll
      for (int u = 0; u < 8; ++u) {
        const float hh = v + (zv[u] - v) * 0.5f;
        const u16 sp16 = (hh >= 1.0f) ? (u16)0x3F80 : (u16)0;
        v = (hh >= 1.0f) ? 0.0f : hh;
        z[((size_t)(((i0 + u) * B_DIM + b) * T_DIM + x)) * D_DIM + h * HD + lane] = sp16;
      }
    }
  }
}

// ---------------------------------------------------------------------------
extern "C" void kernel_launch(void* const* d_in, const int* in_sizes, int n_in,
                              void* d_out, int out_size, void* d_ws, size_t ws_size,
                              hipStream_t stream) {
  const float* q  = (const float*)d_in[0];
  const float* kv = (const float*)d_in[1];
  const float* Wq = (const float*)d_in[2];
  const float* gq = (const float*)d_in[3];
  const float* bq = (const float*)d_in[4];
  const float* Wk = (const float*)d_in[5];
  const float* gk = (const float*)d_in[6];
  const float* bk = (const float*)d_in[7];
  const float* Wv = (const float*)d_in[8];
  const float* gv = (const float*)d_in[9];
  const float* bv = (const float*)d_in[10];
  const float* Wp = (const float*)d_in[11];
  const float* gp = (const float*)d_in[12];
  const float* bp = (const float*)d_in[13];
  float* out = (float*)d_out;
  char* ws = (char*)d_ws;

  // workspace layout (bytes)
  float* Ybuf  = (float*)(ws + 0);                // 50,331,648 (Y); Zb aliases head
  u16*   Zb    = (u16*)(ws + 0);                  // 25,165,824 (bf16 spikes, after Y dead)
  double* part = (double*)(ws + 50331648ull);     //  3,145,728 (up to 512 strips)
  float* ss    = (float*)(ws + 53477376ull);      //      3,072
  u8* qsb      = (u8*)(ws + 53480448ull);         // 12,582,912
  u8* ksb      = (u8*)(ws + 66063360ull);         // 12,582,912
  u8* vsb      = (u8*)(ws + 78646272ull);         // 12,582,912
  char* Wimg   = (char*)(ws + 91229184ull);       //  2,359,296 (4 x 589,824)

  const int G2 = 1536;  // gemm_bn2 grid (3 ntiles x 512 m-strips of 64)
  const int G1 = 768;   // gemm_bn1 grid (3 ntiles x 256 m-strips of 128)

  // --- weight split images (one pass, L2-resident afterwards) ---
  prep_w<<<12, 256, 0, stream>>>(Wq, Wk, Wv, Wp, Wimg);

  // --- q branch ---
  gemm_bn2<<<G2, 256, 0, stream>>>(q, Wimg + 0 * (size_t)IMG_PER_W, Ybuf, part);
  bn_stats_final<<<6, 64, 0, stream>>>(part, gq, bq, ss, 512);
  lif_kernel<0><<<CH / 256, 256, 0, stream>>>(Ybuf, ss, qsb);

  // --- k branch ---
  gemm_bn2<<<G2, 256, 0, stream>>>(kv, Wimg + 1 * (size_t)IMG_PER_W, Ybuf, part);
  bn_stats_final<<<6, 64, 0, stream>>>(part, gk, bk, ss, 512);
  lif_kernel<0><<<CH / 256, 256, 0, stream>>>(Ybuf, ss, ksb);

  // --- v branch ---
  gemm_bn2<<<G2, 256, 0, stream>>>(kv, Wimg + 2 * (size_t)IMG_PER_W, Ybuf, part);
  bn_stats_final<<<6, 64, 0, stream>>>(part, gv, bv, ss, 512);
  lif_kernel<0><<<CH / 256, 256, 0, stream>>>(Ybuf, ss, vsb);

  // --- attention + fused attn_lif -> bf16 spikes in Zb (Ybuf dead) ---
  attn_kernel<<<T_DIM * B_DIM * 2, 256, 0, stream>>>(qsb, ksb, vsb, Zb);

  // --- proj GEMM (binary A, 2 products) -> d_out, stats fused, proj_lif ---
  gemm_bn1<<<G1, 256, 0, stream>>>(Zb, Wimg + 3 * (size_t)IMG_PER_W, out, part);
  bn_stats_final<<<6, 64, 0, stream>>>(part, gp, bp, ss, 256);
  lif_kernel<2><<<CH / 256, 256, 0, stream>>>(out, ss, (u8*)nullptr);
}

// Round 17
// 292.780 us; speedup vs baseline: 2.2172x; 2.2172x over previous
//
#include <hip/hip_runtime.h>

typedef unsigned char u8;
typedef unsigned short u16;
typedef unsigned int u32;
typedef unsigned long long u64;
typedef __attribute__((ext_vector_type(8))) short s16x8;   // 8 bf16 = 4 VGPR
typedef __attribute__((ext_vector_type(4))) float f32x4;   // MFMA acc

#define T_DIM 64
#define B_DIM 8
#define N_DIM 64
#define D_DIM 384
#define H_DIM 8
#define HD 48
#define M_ROWS 32768
#define CH 196608

// W split-image geometry: per W: [ntile 3][kstep 12][split 2][kc 4][n 128][ki 8] bf16
#define IMG_PER_KSTEP 16384            // 1024 chunks * 16B
#define IMG_PER_NTILE (12 * IMG_PER_KSTEP)
#define IMG_PER_W (3 * IMG_PER_NTILE)  // 589824 B

union I4S { int4 i; s16x8 v; };

// ---------------------------------------------------------------------------
// Exact bf16 truncation split helpers
// ---------------------------------------------------------------------------
__device__ __forceinline__ void split8(const float* e, int4& o1, int4& o2, int4& o3) {
  u16 h1[8], h2[8], h3[8];
#pragma unroll
  for (int i = 0; i < 8; ++i) {
    const float x = e[i];
    const u32 b = __float_as_uint(x);
    h1[i] = (u16)(b >> 16);
    const float x1 = __uint_as_float(b & 0xFFFF0000u);
    const float r1 = x - x1;
    const u32 c = __float_as_uint(r1);
    h2[i] = (u16)(c >> 16);
    const float x2 = __uint_as_float(c & 0xFFFF0000u);
    const float r2 = r1 - x2;
    h3[i] = (u16)(__float_as_uint(r2) >> 16);
  }
  o1 = make_int4((int)((u32)h1[0] | ((u32)h1[1] << 16)), (int)((u32)h1[2] | ((u32)h1[3] << 16)),
                 (int)((u32)h1[4] | ((u32)h1[5] << 16)), (int)((u32)h1[6] | ((u32)h1[7] << 16)));
  o2 = make_int4((int)((u32)h2[0] | ((u32)h2[1] << 16)), (int)((u32)h2[2] | ((u32)h2[3] << 16)),
                 (int)((u32)h2[4] | ((u32)h2[5] << 16)), (int)((u32)h2[6] | ((u32)h2[7] << 16)));
  o3 = make_int4((int)((u32)h3[0] | ((u32)h3[1] << 16)), (int)((u32)h3[2] | ((u32)h3[3] << 16)),
                 (int)((u32)h3[4] | ((u32)h3[5] << 16)), (int)((u32)h3[6] | ((u32)h3[7] << 16)));
}

// 2-way split only (A-side)
__device__ __forceinline__ void split8_2(const float* e, int4& o1, int4& o2) {
  u16 h1[8], h2[8];
#pragma unroll
  for (int i = 0; i < 8; ++i) {
    const float x = e[i];
    const u32 b = __float_as_uint(x);
    h1[i] = (u16)(b >> 16);
    const float x1 = __uint_as_float(b & 0xFFFF0000u);
    const float r1 = x - x1;
    h2[i] = (u16)(__float_as_uint(r1) >> 16);
  }
  o1 = make_int4((int)((u32)h1[0] | ((u32)h1[1] << 16)), (int)((u32)h1[2] | ((u32)h1[3] << 16)),
                 (int)((u32)h1[4] | ((u32)h1[5] << 16)), (int)((u32)h1[6] | ((u32)h1[7] << 16)));
  o2 = make_int4((int)((u32)h2[0] | ((u32)h2[1] << 16)), (int)((u32)h2[2] | ((u32)h2[3] << 16)),
                 (int)((u32)h2[4] | ((u32)h2[5] << 16)), (int)((u32)h2[6] | ((u32)h2[7] << 16)));
}

__device__ __forceinline__ void split1(float xx, u16& a, u16& b2, u16& c) {
  const u32 u = __float_as_uint(xx);
  a = (u16)(u >> 16);
  const float x1 = __uint_as_float(u & 0xFFFF0000u);
  const float r1 = xx - x1;
  const u32 u2 = __float_as_uint(r1);
  b2 = (u16)(u2 >> 16);
  const float x2 = __uint_as_float(u2 & 0xFFFF0000u);
  const float r2 = r1 - x2;
  c = (u16)(__float_as_uint(r2) >> 16);
}

__device__ __forceinline__ u64 packmask48(const u8* p) {
  const int4 r0 = ((const int4*)p)[0];
  const int4 r1 = ((const int4*)p)[1];
  const int4 r2 = ((const int4*)p)[2];
  u32 wv[12] = {(u32)r0.x, (u32)r0.y, (u32)r0.z, (u32)r0.w,
                (u32)r1.x, (u32)r1.y, (u32)r1.z, (u32)r1.w,
                (u32)r2.x, (u32)r2.y, (u32)r2.z, (u32)r2.w};
  u64 bits = 0;
#pragma unroll
  for (int w = 0; w < 12; ++w) {
    const u32 u = wv[w];
    const u32 nib = (u & 1u) | ((u >> 7) & 2u) | ((u >> 14) & 4u) | ((u >> 21) & 8u);
    bits |= (u64)nib << (w * 4);
  }
  return bits;
}

// ---------------------------------------------------------------------------
// prep_w: split weight matrices into 2-split fragment-image layout (swizzled).
// ---------------------------------------------------------------------------
__global__ __launch_bounds__(256) void prep_w(const float* __restrict__ W0,
                                              const float* __restrict__ W1,
                                              const float* __restrict__ W2,
                                              const float* __restrict__ W3,
                                              char* __restrict__ img) {
  const int widx = blockIdx.x & 3;
  const int nt = blockIdx.x >> 2;
  const float* W = (widx == 0) ? W0 : (widx == 1) ? W1 : (widx == 2) ? W2 : W3;
  char* base = img + (size_t)widx * IMG_PER_W + (size_t)nt * IMG_PER_NTILE;
  const int tid = threadIdx.x;
  const int nr = tid >> 1;
  const int kh = tid & 1;
  for (int ks = 0; ks < 12; ++ks) {
    const float* src = W + (size_t)(nt * 128 + nr) * D_DIM + ks * 32 + kh * 16;
    float4 v0 = ((const float4*)src)[0];
    float4 v1 = ((const float4*)src)[1];
    float4 v2 = ((const float4*)src)[2];
    float4 v3 = ((const float4*)src)[3];
    float e[16] = {v0.x, v0.y, v0.z, v0.w, v1.x, v1.y, v1.z, v1.w,
                   v2.x, v2.y, v2.z, v2.w, v3.x, v3.y, v3.z, v3.w};
    int4* dst = (int4*)(base + (size_t)ks * IMG_PER_KSTEP);
#pragma unroll
    for (int sub = 0; sub < 2; ++sub) {
      const int kc = kh * 2 + sub;
      int4 o1, o2, o3;
      split8(e + sub * 8, o1, o2, o3);
      dst[(0 * 4 + kc) * 128 + (nr ^ kc)] = o1;
      dst[(1 * 4 + kc) * 128 + (nr ^ kc)] = o2;
    }
  }
}

// ---------------------------------------------------------------------------
// gemm_bn2 (qkv): BM=64 x BN=128 tile, 2x2 waves (wave tile 32x64), BK=32.
// A f32 split-staged (2 planes) + B image, BOTH double-buffered in LDS
// (48 KB -> 3 blocks/CU), ONE barrier per K-step. Products per acc:
// (A1,B0),(A0,B1),(A0,B0). Grid 1536, XCD swizzle. 512 strips of 64 rows.
// ---------------------------------------------------------------------------
__global__ __launch_bounds__(256) void gemm_bn2(const float* __restrict__ A,
                                                const char* __restrict__ imgW,
                                                float* __restrict__ C,
                                                double* __restrict__ part) {
  __shared__ __align__(16) char shraw[49152];  // B[2][16KB] @0, A[2][8KB] @32768
  int4* BchW = (int4*)shraw;
  const s16x8* BchR = (const s16x8*)shraw;
  int4* AchW = (int4*)shraw + 2048;            // byte 32768
  const s16x8* AchR = (const s16x8*)shraw + 2048;

  const int tid = threadIdx.x;
  const int lane = tid & 63;
  const int w = tid >> 6;
  const int wm = w >> 1, wn = w & 1;
  const int lr = lane & 15;
  const int kcL = lane >> 4;

  const int wgid = blockIdx.x;
  const int xcdSlot = wgid & 7;
  const int inner = wgid >> 3;          // [0,192)
  const int ntx = inner % 3;
  const int by = (inner / 3) * 8 + xcdSlot;   // [0,512)
  const int bn = ntx * 128;
  const int bm = by * 64;

  const int4* imgI = (const int4*)(imgW + (size_t)ntx * IMG_PER_NTILE);

  int axc[2], bxc[4];
#pragma unroll
  for (int f = 0; f < 2; ++f)
    axc[f] = kcL * 64 + ((wm * 32 + f * 16 + lr) ^ kcL);
#pragma unroll
  for (int f = 0; f < 4; ++f)
    bxc[f] = kcL * 128 + ((wn * 64 + f * 16 + lr) ^ kcL);

  float4 a0, a1;
  int4 b0, b1, b2, b3;
  const int arow = tid >> 2;           // 0..63
  const int akc = tid & 3;             // k-chunk 0..3 (8 elems each)

#define LOADA(ks)                                                             \
  do {                                                                        \
    const float* ap = A + (size_t)(bm + arow) * D_DIM + (ks) * 32 + akc * 8;  \
    a0 = ((const float4*)ap)[0];                                              \
    a1 = ((const float4*)ap)[1];                                              \
  } while (0)

#define LOADB(ks)                                                             \
  do {                                                                        \
    b0 = imgI[(ks) * 1024 + tid];                                             \
    b1 = imgI[(ks) * 1024 + tid + 256];                                       \
    b2 = imgI[(ks) * 1024 + tid + 512];                                       \
    b3 = imgI[(ks) * 1024 + tid + 768];                                       \
  } while (0)

#define WRITES(buf)                                                           \
  do {                                                                        \
    float e[8] = {a0.x, a0.y, a0.z, a0.w, a1.x, a1.y, a1.z, a1.w};            \
    int4 o1, o2;                                                              \
    split8_2(e, o1, o2);                                                      \
    AchW[(buf) * 512 + 0 * 256 + akc * 64 + (arow ^ akc)] = o1;               \
    AchW[(buf) * 512 + 1 * 256 + akc * 64 + (arow ^ akc)] = o2;               \
    BchW[(buf) * 1024 + tid] = b0;                                            \
    BchW[(buf) * 1024 + tid + 256] = b1;                                      \
    BchW[(buf) * 1024 + tid + 512] = b2;                                      \
    BchW[(buf) * 1024 + tid + 768] = b3;                                      \
  } while (0)

  f32x4 acc[2][4] = {};

  LOADA(0); LOADB(0);
  WRITES(0);
  __syncthreads();

  int cur = 0;
  for (int ks = 0; ks < 12; ++ks) {
    if (ks < 11) { LOADA(ks + 1); LOADB(ks + 1); }
    s16x8 af[2][2];
#pragma unroll
    for (int s = 0; s < 2; ++s)
#pragma unroll
      for (int fm = 0; fm < 2; ++fm)
        af[s][fm] = AchR[cur * 512 + s * 256 + axc[fm]];
#pragma unroll
    for (int fn = 0; fn < 4; ++fn) {
      const s16x8 bf0 = BchR[cur * 1024 + bxc[fn]];
      const s16x8 bf1 = BchR[cur * 1024 + 512 + bxc[fn]];
#pragma unroll
      for (int fm = 0; fm < 2; ++fm)
        acc[fm][fn] = __builtin_amdgcn_mfma_f32_16x16x32_bf16(af[1][fm], bf0, acc[fm][fn], 0, 0, 0);
#pragma unroll
      for (int fm = 0; fm < 2; ++fm)
        acc[fm][fn] = __builtin_amdgcn_mfma_f32_16x16x32_bf16(af[0][fm], bf1, acc[fm][fn], 0, 0, 0);
#pragma unroll
      for (int fm = 0; fm < 2; ++fm)
        acc[fm][fn] = __builtin_amdgcn_mfma_f32_16x16x32_bf16(af[0][fm], bf0, acc[fm][fn], 0, 0, 0);
    }
    if (ks < 11) {
      WRITES(cur ^ 1);
      __syncthreads();
      cur ^= 1;
    }
  }
#undef LOADA
#undef LOADB
#undef WRITES

#pragma unroll
  for (int fm = 0; fm < 2; ++fm)
#pragma unroll
    for (int fn = 0; fn < 4; ++fn) {
      const int row = bm + wm * 32 + fm * 16 + kcL * 4;
      const int col = bn + wn * 64 + fn * 16 + lr;
#pragma unroll
      for (int r = 0; r < 4; ++r)
        C[(size_t)(row + r) * D_DIM + col] = acc[fm][fn][r];
    }

  __syncthreads();
  double* red = (double*)shraw;
#pragma unroll
  for (int fn = 0; fn < 4; ++fn) {
    const int col = wn * 64 + fn * 16 + lr;
    const int rg = wm * 4 + kcL;
    double s = 0.0, qd = 0.0;
#pragma unroll
    for (int fm = 0; fm < 2; ++fm)
#pragma unroll
      for (int r = 0; r < 4; ++r) {
        const double v = (double)acc[fm][fn][r];
        s += v;
        qd += v * v;
      }
    red[(rg * 128 + col) * 2 + 0] = s;
    red[(rg * 128 + col) * 2 + 1] = qd;
  }
  __syncthreads();
  if (tid < 128) {
    double S = 0.0, Q = 0.0;
#pragma unroll
    for (int rg = 0; rg < 8; ++rg) {
      S += red[(rg * 128 + tid) * 2 + 0];
      Q += red[(rg * 128 + tid) * 2 + 1];
    }
    const size_t pidx = ((size_t)by * D_DIM + bn + tid) * 2;
    part[pidx + 0] = S;
    part[pidx + 1] = Q;
  }
}

// ---------------------------------------------------------------------------
// gemm_bn1 (proj): BM=128 x BN=128; A = bf16 spikes (exact) via LDS, B via
// LDS, BOTH double-buffered, ONE barrier per K-step. 2 products. Grid 768.
// ---------------------------------------------------------------------------
__global__ __launch_bounds__(256) void gemm_bn1(const u16* __restrict__ Zb,
                                                const char* __restrict__ imgW,
                                                float* __restrict__ C,
                                                double* __restrict__ part) {
  __shared__ __align__(16) char shraw[49152];   // B[2][16384] @0, A[2][8192] @32768
  int4* BchW = (int4*)shraw;
  const s16x8* BchR = (const s16x8*)shraw;
  int4* AchW = (int4*)shraw + 2048;
  const s16x8* AchR = (const s16x8*)shraw + 2048;

  const int tid = threadIdx.x;
  const int lane = tid & 63;
  const int w = tid >> 6;
  const int wm = w >> 1, wn = w & 1;
  const int lr = lane & 15;
  const int kcL = lane >> 4;

  const int wgid = blockIdx.x;
  const int xcdSlot = wgid & 7;
  const int inner = wgid >> 3;
  const int ntx = inner % 3;
  const int by = (inner / 3) * 8 + xcdSlot;   // [0,256)
  const int bn = ntx * 128;
  const int bm = by * 128;

  const int4* imgI = (const int4*)(imgW + (size_t)ntx * IMG_PER_NTILE);

  int axc[4], bxc[4];
#pragma unroll
  for (int f = 0; f < 4; ++f) {
    axc[f] = kcL * 128 + ((wm * 64 + f * 16 + lr) ^ kcL);
    bxc[f] = kcL * 128 + ((wn * 64 + f * 16 + lr) ^ kcL);
  }

  int4 za0, za1;
  int4 b0, b1, b2, b3;
  const int c0 = tid, c1 = tid + 256;

#define LOADA1(ks)                                                            \
  do {                                                                        \
    { const int kc = c0 >> 7, mp = c0 & 127;                                  \
      za0 = *(const int4*)(Zb + (size_t)(bm + (mp ^ kc)) * D_DIM +            \
                           (ks) * 32 + kc * 8); }                             \
    { const int kc = c1 >> 7, mp = c1 & 127;                                  \
      za1 = *(const int4*)(Zb + (size_t)(bm + (mp ^ kc)) * D_DIM +            \
                           (ks) * 32 + kc * 8); }                             \
  } while (0)

#define WRITEA1(buf)                                                          \
  do {                                                                        \
    AchW[(buf) * 512 + c0] = za0;                                             \
    AchW[(buf) * 512 + c1] = za1;                                             \
  } while (0)

#define LOADB1(ks)                                                            \
  do {                                                                        \
    b0 = imgI[(ks) * 1024 + tid];                                             \
    b1 = imgI[(ks) * 1024 + tid + 256];                                       \
    b2 = imgI[(ks) * 1024 + tid + 512];                                       \
    b3 = imgI[(ks) * 1024 + tid + 768];                                       \
  } while (0)

#define WRITEB1(buf)                                                          \
  do {                                                                        \
    BchW[(buf) * 1024 + tid] = b0;                                            \
    BchW[(buf) * 1024 + tid + 256] = b1;                                      \
    BchW[(buf) * 1024 + tid + 512] = b2;                                      \
    BchW[(buf) * 1024 + tid + 768] = b3;                                      \
  } while (0)

  f32x4 acc[4][4] = {};

  LOADA1(0);
  LOADB1(0);
  WRITEA1(0);
  WRITEB1(0);
  __syncthreads();

  int cur = 0;
  for (int ks = 0; ks < 12; ++ks) {
    if (ks < 11) { LOADA1(ks + 1); LOADB1(ks + 1); }
    s16x8 af[4];
#pragma unroll
    for (int fm = 0; fm < 4; ++fm) af[fm] = AchR[cur * 512 + axc[fm]];
#pragma unroll
    for (int fn = 0; fn < 4; ++fn) {
      const s16x8 bf0 = BchR[cur * 1024 + bxc[fn]];
      const s16x8 bf1 = BchR[cur * 1024 + 512 + bxc[fn]];
#pragma unroll
      for (int fm = 0; fm < 4; ++fm)
        acc[fm][fn] = __builtin_amdgcn_mfma_f32_16x16x32_bf16(af[fm], bf1, acc[fm][fn], 0, 0, 0);
#pragma unroll
      for (int fm = 0; fm < 4; ++fm)
        acc[fm][fn] = __builtin_amdgcn_mfma_f32_16x16x32_bf16(af[fm], bf0, acc[fm][fn], 0, 0, 0);
    }
    if (ks < 11) {
      WRITEA1(cur ^ 1);
      WRITEB1(cur ^ 1);
      __syncthreads();
      cur ^= 1;
    }
  }
#undef LOADA1
#undef WRITEA1
#undef LOADB1
#undef WRITEB1

#pragma unroll
  for (int fm = 0; fm < 4; ++fm)
#pragma unroll
    for (int fn = 0; fn < 4; ++fn) {
      const int row = bm + wm * 64 + fm * 16 + kcL * 4;
      const int col = bn + wn * 64 + fn * 16 + lr;
#pragma unroll
      for (int r = 0; r < 4; ++r)
        C[(size_t)(row + r) * D_DIM + col] = acc[fm][fn][r];
    }

  __syncthreads();
  double* red = (double*)shraw;
#pragma unroll
  for (int fn = 0; fn < 4; ++fn) {
    const int col = wn * 64 + fn * 16 + lr;
    const int rg = wm * 4 + kcL;
    double s = 0.0, qd = 0.0;
#pragma unroll
    for (int fm = 0; fm < 4; ++fm)
#pragma unroll
      for (int r = 0; r < 4; ++r) {
        const double v = (double)acc[fm][fn][r];
        s += v;
        qd += v * v;
      }
    red[(rg * 128 + col) * 2 + 0] = s;
    red[(rg * 128 + col) * 2 + 1] = qd;
  }
  __syncthreads();
  if (tid < 128) {
    double S = 0.0, Q = 0.0;
#pragma unroll
    for (int rg = 0; rg < 8; ++rg) {
      S += red[(rg * 128 + tid) * 2 + 0];
      Q += red[(rg * 128 + tid) * 2 + 1];
    }
    const size_t pidx = ((size_t)by * D_DIM + bn + tid) * 2;
    part[pidx + 0] = S;
    part[pidx + 1] = Q;
  }
}

// ---------------------------------------------------------------------------
// BN stats finalize (fixed order, f64). NBLK is COMPILE-TIME so the loop
// unrolls and loads pipeline (runtime trip count cost 126 us in r16 —
// one exposed L2 latency per iteration).
// ---------------------------------------------------------------------------
template <int NBLK>
__global__ void bn_stats_final(const double* __restrict__ part,
                               const float* __restrict__ gamma,
                               const float* __restrict__ beta,
                               float* __restrict__ ss) {
  const int c = blockIdx.x * 64 + threadIdx.x;
  double s = 0.0, q = 0.0;
#pragma unroll 16
  for (int b = 0; b < NBLK; ++b) {
    s += part[((size_t)b * D_DIM + c) * 2 + 0];
    q += part[((size_t)b * D_DIM + c) * 2 + 1];
  }
  const double n = (double)M_ROWS;
  const double mean = s / n;
  const double var = q / n - mean * mean;
  const double rstd = 1.0 / sqrt(var + 1e-5);
  const double sc = (double)gamma[c] * rstd;
  ss[c * 2 + 0] = (float)sc;
  ss[c * 2 + 1] = (float)((double)beta[c] - mean * sc);
}

// ---------------------------------------------------------------------------
// LIF scan (64 steps, stride CH). MODE 0: BN+LIF -> u8 spikes.
// MODE 2: BN+LIF in place (f32 spikes).
// ---------------------------------------------------------------------------
template <int MODE>
__global__ __launch_bounds__(256) void lif_kernel(float* Y,
                                                  const float* __restrict__ ss,
                                                  u8* __restrict__ spikes) {
  const int c = blockIdx.x * 256 + threadIdx.x;
  const int dd = c % D_DIM;
  const float scale = ss[dd * 2 + 0];
  const float shift = ss[dd * 2 + 1];
  float v = 0.0f;
  for (int t0 = 0; t0 < T_DIM; t0 += 8) {
    float xs[8];
#pragma unroll
    for (int u = 0; u < 8; ++u) xs[u] = Y[(size_t)(t0 + u) * CH + c];
#pragma unroll
    for (int u = 0; u < 8; ++u) {
      const float xv = xs[u] * scale + shift;
      const float hh = v + (xv - v) * 0.5f;
      const float sp = (hh >= 1.0f) ? 1.0f : 0.0f;
      v = (1.0f - sp) * hh;
      if (MODE == 0)
        spikes[(size_t)(t0 + u) * CH + c] = (u8)sp;
      else
        Y[(size_t)(t0 + u) * CH + c] = sp;
    }
  }
}

// ---------------------------------------------------------------------------
// Attention + fused attn_lif, MFMA version, 4 heads per 256-thread block
// (round-10..16 passing version, unchanged).
// ---------------------------------------------------------------------------
__global__ __launch_bounds__(256) void attn_kernel(const u8* __restrict__ qs,
                                                   const u8* __restrict__ ks,
                                                   const u8* __restrict__ vs,
                                                   u16* __restrict__ z) {
  const int gid = blockIdx.x;          // (x, b, head-group)
  const int hg = (gid & 1) * 4;
  const int b = (gid >> 1) & 7;
  const int x = gid >> 4;
  const int w = threadIdx.x >> 6;
  const int h = hg + w;
  const int lane = threadIdx.x & 63;

  union Slab {
    struct { u64 qm[64]; u64 km[64]; float maskT[64]; u16 vt[48][80]; } a;  // 8960 B
    float zl[64][50];                                                       // 12800 B
  };
  __shared__ Slab sh[4];  // 51200 B
  Slab& S = sh[w];

  {
    const u8* qp = qs + ((size_t)((x * B_DIM + b) * N_DIM + lane)) * D_DIM + h * HD;
    S.a.qm[lane] = packmask48(qp);
    const size_t koff = ((size_t)((lane * B_DIM + b) * N_DIM + x)) * D_DIM + h * HD;
    S.a.km[lane] = packmask48(ks + koff);
    const u8* vp = vs + koff;
    const int4 r0 = ((const int4*)vp)[0];
    const int4 r1 = ((const int4*)vp)[1];
    const int4 r2 = ((const int4*)vp)[2];
    u32 vw[12] = {(u32)r0.x, (u32)r0.y, (u32)r0.z, (u32)r0.w,
                  (u32)r1.x, (u32)r1.y, (u32)r1.z, (u32)r1.w,
                  (u32)r2.x, (u32)r2.y, (u32)r2.z, (u32)r2.w};
#pragma unroll
    for (int ww = 0; ww < 12; ++ww) {
      const u32 u = vw[ww];
#pragma unroll
      for (int e = 0; e < 4; ++e)
        S.a.vt[ww * 4 + e][lane] = ((u >> (8 * e)) & 1u) ? (u16)0x3F80 : (u16)0;
    }
    S.a.maskT[lane] = 1.0f / (float)(1 + lane);
  }
  __syncthreads();

  const int lr = lane & 15;
  const int lg = lane >> 4;
  f32x4 acc[4][3] = {};

  for (int ksi = 0; ksi < 2; ++ksi) {
    const int j0 = lg * 8 + ksi * 32;
    s16x8 bf[3];
#pragma unroll
    for (int nf = 0; nf < 3; ++nf)
      bf[nf] = *(const s16x8*)&S.a.vt[lr + nf * 16][j0];
    s16x8 af[3][4];
#pragma unroll
    for (int mf = 0; mf < 4; ++mf) {
      const int i = lr + mf * 16;
      const u64 qi = S.a.qm[i];
      union { u32 w[4]; s16x8 v; } p1, p2, p3;
#pragma unroll
      for (int pp = 0; pp < 4; ++pp) {
        u16 aa[2], bb[2], cc[2];
#pragma unroll
        for (int e = 0; e < 2; ++e) {
          const int j = j0 + pp * 2 + e;
          const int cnt = __popcll(qi & S.a.km[j]);
          int ad = i - j;
          if (ad < 0) ad = -ad;
          const float sv = (float)cnt * S.a.maskT[ad];
          split1(sv, aa[e], bb[e], cc[e]);
        }
        p1.w[pp] = (u32)aa[0] | ((u32)aa[1] << 16);
        p2.w[pp] = (u32)bb[0] | ((u32)bb[1] << 16);
        p3.w[pp] = (u32)cc[0] | ((u32)cc[1] << 16);
      }
      af[0][mf] = p1.v;
      af[1][mf] = p2.v;
      af[2][mf] = p3.v;
    }
#pragma unroll
    for (int spi = 0; spi < 3; ++spi) {
      const int sp = 2 - spi;
#pragma unroll
      for (int nf = 0; nf < 3; ++nf)
#pragma unroll
        for (int mf = 0; mf < 4; ++mf)
          acc[mf][nf] = __builtin_amdgcn_mfma_f32_16x16x32_bf16(af[sp][mf], bf[nf],
                                                                acc[mf][nf], 0, 0, 0);
    }
  }
  __syncthreads();

  const float kScale = 0.05103103630798287f;  // 384^-0.5
#pragma unroll
  for (int mf = 0; mf < 4; ++mf)
#pragma unroll
    for (int nf = 0; nf < 3; ++nf)
#pragma unroll
      for (int r = 0; r < 4; ++r)
        S.zl[mf * 16 + lg * 4 + r][lr + nf * 16] = acc[mf][nf][r] * kScale;
  __syncthreads();

  if (lane < HD) {
    float v = 0.0f;
    for (int i0 = 0; i0 < 64; i0 += 8) {
      float zv[8];
#pragma unroll
      for (int u = 0; u < 8; ++u) zv[u] = S.zl[i0 + u][lane];
#pragma unroll
      for (int u = 0; u < 8; ++u) {
        const float hh = v + (zv[u] - v) * 0.5f;
        const u16 sp16 = (hh >= 1.0f) ? (u16)0x3F80 : (u16)0;
        v = (hh >= 1.0f) ? 0.0f : hh;
        z[((size_t)(((i0 + u) * B_DIM + b) * T_DIM + x)) * D_DIM + h * HD + lane] = sp16;
      }
    }
  }
}

// ---------------------------------------------------------------------------
extern "C" void kernel_launch(void* const* d_in, const int* in_sizes, int n_in,
                              void* d_out, int out_size, void* d_ws, size_t ws_size,
                              hipStream_t stream) {
  const float* q  = (const float*)d_in[0];
  const float* kv = (const float*)d_in[1];
  const float* Wq = (const float*)d_in[2];
  const float* gq = (const float*)d_in[3];
  const float* bq = (const float*)d_in[4];
  const float* Wk = (const float*)d_in[5];
  const float* gk = (const float*)d_in[6];
  const float* bk = (const float*)d_in[7];
  const float* Wv = (const float*)d_in[8];
  const float* gv = (const float*)d_in[9];
  const float* bv = (const float*)d_in[10];
  const float* Wp = (const float*)d_in[11];
  const float* gp = (const float*)d_in[12];
  const float* bp = (const float*)d_in[13];
  float* out = (float*)d_out;
  char* ws = (char*)d_ws;

  // workspace layout (bytes)
  float* Ybuf  = (float*)(ws + 0);                // 50,331,648 (Y); Zb aliases head
  u16*   Zb    = (u16*)(ws + 0);                  // 25,165,824 (bf16 spikes, after Y dead)
  double* part = (double*)(ws + 50331648ull);     //  3,145,728 (up to 512 strips)
  float* ss    = (float*)(ws + 53477376ull);      //      3,072
  u8* qsb      = (u8*)(ws + 53480448ull);         // 12,582,912
  u8* ksb      = (u8*)(ws + 66063360ull);         // 12,582,912
  u8* vsb      = (u8*)(ws + 78646272ull);         // 12,582,912
  char* Wimg   = (char*)(ws + 91229184ull);       //  2,359,296 (4 x 589,824)

  const int G2 = 1536;  // gemm_bn2 grid (3 ntiles x 512 m-strips of 64)
  const int G1 = 768;   // gemm_bn1 grid (3 ntiles x 256 m-strips of 128)

  // --- weight split images (one pass, L2-resident afterwards) ---
  prep_w<<<12, 256, 0, stream>>>(Wq, Wk, Wv, Wp, Wimg);

  // --- q branch ---
  gemm_bn2<<<G2, 256, 0, stream>>>(q, Wimg + 0 * (size_t)IMG_PER_W, Ybuf, part);
  bn_stats_final<512><<<6, 64, 0, stream>>>(part, gq, bq, ss);
  lif_kernel<0><<<CH / 256, 256, 0, stream>>>(Ybuf, ss, qsb);

  // --- k branch ---
  gemm_bn2<<<G2, 256, 0, stream>>>(kv, Wimg + 1 * (size_t)IMG_PER_W, Ybuf, part);
  bn_stats_final<512><<<6, 64, 0, stream>>>(part, gk, bk, ss);
  lif_kernel<0><<<CH / 256, 256, 0, stream>>>(Ybuf, ss, ksb);

  // --- v branch ---
  gemm_bn2<<<G2, 256, 0, stream>>>(kv, Wimg + 2 * (size_t)IMG_PER_W, Ybuf, part);
  bn_stats_final<512><<<6, 64, 0, stream>>>(part, gv, bv, ss);
  lif_kernel<0><<<CH / 256, 256, 0, stream>>>(Ybuf, ss, vsb);

  // --- attention + fused attn_lif -> bf16 spikes in Zb (Ybuf dead) ---
  attn_kernel<<<T_DIM * B_DIM * 2, 256, 0, stream>>>(qsb, ksb, vsb, Zb);

  // --- proj GEMM (binary A, 2 products) -> d_out, stats fused, proj_lif ---
  gemm_bn1<<<G1, 256, 0, stream>>>(Zb, Wimg + 3 * (size_t)IMG_PER_W, out, part);
  bn_stats_final<256><<<6, 64, 0, stream>>>(part, gp, bp, ss);
  lif_kernel<2><<<CH / 256, 256, 0, stream>>>(out, ss, (u8*)nullptr);
}

// Round 18
// 249.043 us; speedup vs baseline: 2.6066x; 1.1756x over previous
//
#include <hip/hip_runtime.h>

typedef unsigned char u8;
typedef unsigned short u16;
typedef unsigned int u32;
typedef unsigned long long u64;
typedef __attribute__((ext_vector_type(8))) short s16x8;   // 8 bf16 = 4 VGPR
typedef __attribute__((ext_vector_type(4))) float f32x4;   // MFMA acc

#define T_DIM 64
#define B_DIM 8
#define N_DIM 64
#define D_DIM 384
#define H_DIM 8
#define HD 48
#define M_ROWS 32768
#define CH 196608

// W split-image geometry: per W: [ntile 3][kstep 12][split 2][kc 4][n 128][ki 8] bf16
#define IMG_PER_KSTEP 16384            // 1024 chunks * 16B
#define IMG_PER_NTILE (12 * IMG_PER_KSTEP)
#define IMG_PER_W (3 * IMG_PER_NTILE)  // 589824 B

// ---------------------------------------------------------------------------
// Exact bf16 truncation split helpers
// ---------------------------------------------------------------------------
__device__ __forceinline__ void split8(const float* e, int4& o1, int4& o2, int4& o3) {
  u16 h1[8], h2[8], h3[8];
#pragma unroll
  for (int i = 0; i < 8; ++i) {
    const float x = e[i];
    const u32 b = __float_as_uint(x);
    h1[i] = (u16)(b >> 16);
    const float x1 = __uint_as_float(b & 0xFFFF0000u);
    const float r1 = x - x1;
    const u32 c = __float_as_uint(r1);
    h2[i] = (u16)(c >> 16);
    const float x2 = __uint_as_float(c & 0xFFFF0000u);
    const float r2 = r1 - x2;
    h3[i] = (u16)(__float_as_uint(r2) >> 16);
  }
  o1 = make_int4((int)((u32)h1[0] | ((u32)h1[1] << 16)), (int)((u32)h1[2] | ((u32)h1[3] << 16)),
                 (int)((u32)h1[4] | ((u32)h1[5] << 16)), (int)((u32)h1[6] | ((u32)h1[7] << 16)));
  o2 = make_int4((int)((u32)h2[0] | ((u32)h2[1] << 16)), (int)((u32)h2[2] | ((u32)h2[3] << 16)),
                 (int)((u32)h2[4] | ((u32)h2[5] << 16)), (int)((u32)h2[6] | ((u32)h2[7] << 16)));
  o3 = make_int4((int)((u32)h3[0] | ((u32)h3[1] << 16)), (int)((u32)h3[2] | ((u32)h3[3] << 16)),
                 (int)((u32)h3[4] | ((u32)h3[5] << 16)), (int)((u32)h3[6] | ((u32)h3[7] << 16)));
}

// 2-way split only (A-side)
__device__ __forceinline__ void split8_2(const float* e, int4& o1, int4& o2) {
  u16 h1[8], h2[8];
#pragma unroll
  for (int i = 0; i < 8; ++i) {
    const float x = e[i];
    const u32 b = __float_as_uint(x);
    h1[i] = (u16)(b >> 16);
    const float x1 = __uint_as_float(b & 0xFFFF0000u);
    const float r1 = x - x1;
    h2[i] = (u16)(__float_as_uint(r1) >> 16);
  }
  o1 = make_int4((int)((u32)h1[0] | ((u32)h1[1] << 16)), (int)((u32)h1[2] | ((u32)h1[3] << 16)),
                 (int)((u32)h1[4] | ((u32)h1[5] << 16)), (int)((u32)h1[6] | ((u32)h1[7] << 16)));
  o2 = make_int4((int)((u32)h2[0] | ((u32)h2[1] << 16)), (int)((u32)h2[2] | ((u32)h2[3] << 16)),
                 (int)((u32)h2[4] | ((u32)h2[5] << 16)), (int)((u32)h2[6] | ((u32)h2[7] << 16)));
}

__device__ __forceinline__ void split1(float xx, u16& a, u16& b2, u16& c) {
  const u32 u = __float_as_uint(xx);
  a = (u16)(u >> 16);
  const float x1 = __uint_as_float(u & 0xFFFF0000u);
  const float r1 = xx - x1;
  const u32 u2 = __float_as_uint(r1);
  b2 = (u16)(u2 >> 16);
  const float x2 = __uint_as_float(u2 & 0xFFFF0000u);
  const float r2 = r1 - x2;
  c = (u16)(__float_as_uint(r2) >> 16);
}

__device__ __forceinline__ u64 packmask48(const u8* p) {
  const int4 r0 = ((const int4*)p)[0];
  const int4 r1 = ((const int4*)p)[1];
  const int4 r2 = ((const int4*)p)[2];
  u32 wv[12] = {(u32)r0.x, (u32)r0.y, (u32)r0.z, (u32)r0.w,
                (u32)r1.x, (u32)r1.y, (u32)r1.z, (u32)r1.w,
                (u32)r2.x, (u32)r2.y, (u32)r2.z, (u32)r2.w};
  u64 bits = 0;
#pragma unroll
  for (int w = 0; w < 12; ++w) {
    const u32 u = wv[w];
    const u32 nib = (u & 1u) | ((u >> 7) & 2u) | ((u >> 14) & 4u) | ((u >> 21) & 8u);
    bits |= (u64)nib << (w * 4);
  }
  return bits;
}

// ---------------------------------------------------------------------------
// prep_w: split weight matrices into 2-split fragment-image layout (swizzled).
// ---------------------------------------------------------------------------
__global__ __launch_bounds__(256) void prep_w(const float* __restrict__ W0,
                                              const float* __restrict__ W1,
                                              const float* __restrict__ W2,
                                              const float* __restrict__ W3,
                                              char* __restrict__ img) {
  const int widx = blockIdx.x & 3;
  const int nt = blockIdx.x >> 2;
  const float* W = (widx == 0) ? W0 : (widx == 1) ? W1 : (widx == 2) ? W2 : W3;
  char* base = img + (size_t)widx * IMG_PER_W + (size_t)nt * IMG_PER_NTILE;
  const int tid = threadIdx.x;
  const int nr = tid >> 1;
  const int kh = tid & 1;
  for (int ks = 0; ks < 12; ++ks) {
    const float* src = W + (size_t)(nt * 128 + nr) * D_DIM + ks * 32 + kh * 16;
    float4 v0 = ((const float4*)src)[0];
    float4 v1 = ((const float4*)src)[1];
    float4 v2 = ((const float4*)src)[2];
    float4 v3 = ((const float4*)src)[3];
    float e[16] = {v0.x, v0.y, v0.z, v0.w, v1.x, v1.y, v1.z, v1.w,
                   v2.x, v2.y, v2.z, v2.w, v3.x, v3.y, v3.z, v3.w};
    int4* dst = (int4*)(base + (size_t)ks * IMG_PER_KSTEP);
#pragma unroll
    for (int sub = 0; sub < 2; ++sub) {
      const int kc = kh * 2 + sub;
      int4 o1, o2, o3;
      split8(e + sub * 8, o1, o2, o3);
      dst[(0 * 4 + kc) * 128 + (nr ^ kc)] = o1;
      dst[(1 * 4 + kc) * 128 + (nr ^ kc)] = o2;
    }
  }
}

// ---------------------------------------------------------------------------
// XCD-locality swizzle decode: wgid%8 == by%8 for all 3 ntile-blocks of one
// A m-strip -> same XCD, A L2-shared.
// ---------------------------------------------------------------------------
__device__ __forceinline__ void decode_wg(int wgid, int& ntx, int& by) {
  const int xcdSlot = wgid & 7;
  const int inner = wgid >> 3;
  ntx = inner % 3;
  by = (inner / 3) * 8 + xcdSlot;
}

// ---------------------------------------------------------------------------
// gemm_bn2 (qkv) — round-12 proven version (52 us): 128x128 tile, 2x2 waves,
// A f32 split in LDS staging, single-buffered A+B, 2 barriers per K-step,
// 32 KB LDS -> high occupancy. 3 products: (A1,B0),(A0,B1),(A0,B0).
// ---------------------------------------------------------------------------
__global__ __launch_bounds__(256) void gemm_bn2(const float* __restrict__ A,
                                                const char* __restrict__ imgW,
                                                float* __restrict__ C,
                                                double* __restrict__ part) {
  __shared__ __align__(16) char shraw[32768];   // A planes 16KB + B 16KB
  int4* AchW = (int4*)shraw;
  int4* BchW = (int4*)(shraw + 16384);
  const s16x8* AchR = (const s16x8*)shraw;
  const s16x8* BchR = (const s16x8*)(shraw + 16384);

  const int tid = threadIdx.x;
  const int lane = tid & 63;
  const int w = tid >> 6;
  const int wm = w >> 1, wn = w & 1;
  const int lr = lane & 15;
  const int kcL = lane >> 4;

  int ntx, by;
  decode_wg(blockIdx.x, ntx, by);
  const int bn = ntx * 128;
  const int bm = by * 128;

  const int4* imgI = (const int4*)(imgW + (size_t)ntx * IMG_PER_NTILE);

  int axc[4], bxc[4];
#pragma unroll
  for (int f = 0; f < 4; ++f) {
    axc[f] = kcL * 128 + ((wm * 64 + f * 16 + lr) ^ kcL);
    bxc[f] = kcL * 128 + ((wn * 64 + f * 16 + lr) ^ kcL);
  }

  float4 a0, a1, a2, a3;
  int4 b0, b1, b2, b3;
  const int arow = tid >> 1, akh = tid & 1;

#define LOADA(ks)                                                             \
  do {                                                                        \
    const float* ap = A + (size_t)(bm + arow) * D_DIM + (ks) * 32 + akh * 16; \
    a0 = ((const float4*)ap)[0]; a1 = ((const float4*)ap)[1];                 \
    a2 = ((const float4*)ap)[2]; a3 = ((const float4*)ap)[3];                 \
  } while (0)

#define LOADB(ks)                                                             \
  do {                                                                        \
    b0 = imgI[(ks) * 1024 + tid];                                             \
    b1 = imgI[(ks) * 1024 + tid + 256];                                       \
    b2 = imgI[(ks) * 1024 + tid + 512];                                       \
    b3 = imgI[(ks) * 1024 + tid + 768];                                       \
  } while (0)

#define WRITES()                                                              \
  do {                                                                        \
    float e0[8] = {a0.x, a0.y, a0.z, a0.w, a1.x, a1.y, a1.z, a1.w};           \
    float e1[8] = {a2.x, a2.y, a2.z, a2.w, a3.x, a3.y, a3.z, a3.w};           \
    int4 o1, o2;                                                              \
    { const int kc = akh * 2;                                                 \
      split8_2(e0, o1, o2);                                                   \
      AchW[0 * 512 + kc * 128 + (arow ^ kc)] = o1;                            \
      AchW[1 * 512 + kc * 128 + (arow ^ kc)] = o2; }                          \
    { const int kc = akh * 2 + 1;                                             \
      split8_2(e1, o1, o2);                                                   \
      AchW[0 * 512 + kc * 128 + (arow ^ kc)] = o1;                            \
      AchW[1 * 512 + kc * 128 + (arow ^ kc)] = o2; }                          \
    BchW[tid] = b0; BchW[tid + 256] = b1;                                     \
    BchW[tid + 512] = b2; BchW[tid + 768] = b3;                               \
  } while (0)

  f32x4 acc[4][4] = {};

  LOADA(0); LOADB(0);
  WRITES();
  __syncthreads();

  for (int ks = 0; ks < 12; ++ks) {
    if (ks < 11) { LOADA(ks + 1); LOADB(ks + 1); }
    s16x8 af[2][4];
#pragma unroll
    for (int s = 0; s < 2; ++s)
#pragma unroll
      for (int fm = 0; fm < 4; ++fm) af[s][fm] = AchR[s * 512 + axc[fm]];
#pragma unroll
    for (int fn = 0; fn < 4; ++fn) {
      const s16x8 bf0 = BchR[bxc[fn]];
      const s16x8 bf1 = BchR[512 + bxc[fn]];
#pragma unroll
      for (int fm = 0; fm < 4; ++fm)
        acc[fm][fn] = __builtin_amdgcn_mfma_f32_16x16x32_bf16(af[1][fm], bf0, acc[fm][fn], 0, 0, 0);
#pragma unroll
      for (int fm = 0; fm < 4; ++fm)
        acc[fm][fn] = __builtin_amdgcn_mfma_f32_16x16x32_bf16(af[0][fm], bf1, acc[fm][fn], 0, 0, 0);
#pragma unroll
      for (int fm = 0; fm < 4; ++fm)
        acc[fm][fn] = __builtin_amdgcn_mfma_f32_16x16x32_bf16(af[0][fm], bf0, acc[fm][fn], 0, 0, 0);
    }
    __syncthreads();
    if (ks < 11) {
      WRITES();
      __syncthreads();
    }
  }
#undef LOADA
#undef LOADB
#undef WRITES

#pragma unroll
  for (int fm = 0; fm < 4; ++fm)
#pragma unroll
    for (int fn = 0; fn < 4; ++fn) {
      const int row = bm + wm * 64 + fm * 16 + kcL * 4;
      const int col = bn + wn * 64 + fn * 16 + lr;
#pragma unroll
      for (int r = 0; r < 4; ++r)
        C[(size_t)(row + r) * D_DIM + col] = acc[fm][fn][r];
    }

  __syncthreads();
  double* red = (double*)shraw;
#pragma unroll
  for (int fn = 0; fn < 4; ++fn) {
    const int col = wn * 64 + fn * 16 + lr;
    const int rg = wm * 4 + kcL;
    double s = 0.0, qd = 0.0;
#pragma unroll
    for (int fm = 0; fm < 4; ++fm)
#pragma unroll
      for (int r = 0; r < 4; ++r) {
        const double v = (double)acc[fm][fn][r];
        s += v;
        qd += v * v;
      }
    red[(rg * 128 + col) * 2 + 0] = s;
    red[(rg * 128 + col) * 2 + 1] = qd;
  }
  __syncthreads();
  if (tid < 128) {
    double S = 0.0, Q = 0.0;
#pragma unroll
    for (int rg = 0; rg < 8; ++rg) {
      S += red[(rg * 128 + tid) * 2 + 0];
      Q += red[(rg * 128 + tid) * 2 + 1];
    }
    const size_t pidx = ((size_t)by * D_DIM + bn + tid) * 2;
    part[pidx + 0] = S;
    part[pidx + 1] = Q;
  }
}

// ---------------------------------------------------------------------------
// gemm_bn1 (proj) — round-13 proven version (~21 us): A bf16 spikes + B both
// double-buffered in LDS (48 KB), ONE barrier per K-step. 2 products.
// ---------------------------------------------------------------------------
__global__ __launch_bounds__(256) void gemm_bn1(const u16* __restrict__ Zb,
                                                const char* __restrict__ imgW,
                                                float* __restrict__ C,
                                                double* __restrict__ part) {
  __shared__ __align__(16) char shraw[49152];   // B[2][16384] @0, A[2][8192] @32768
  int4* BchW = (int4*)shraw;
  const s16x8* BchR = (const s16x8*)shraw;
  int4* AchW = (int4*)shraw + 2048;
  const s16x8* AchR = (const s16x8*)shraw + 2048;

  const int tid = threadIdx.x;
  const int lane = tid & 63;
  const int w = tid >> 6;
  const int wm = w >> 1, wn = w & 1;
  const int lr = lane & 15;
  const int kcL = lane >> 4;

  int ntx, by;
  decode_wg(blockIdx.x, ntx, by);
  const int bn = ntx * 128;
  const int bm = by * 128;

  const int4* imgI = (const int4*)(imgW + (size_t)ntx * IMG_PER_NTILE);

  int axc[4], bxc[4];
#pragma unroll
  for (int f = 0; f < 4; ++f) {
    axc[f] = kcL * 128 + ((wm * 64 + f * 16 + lr) ^ kcL);
    bxc[f] = kcL * 128 + ((wn * 64 + f * 16 + lr) ^ kcL);
  }

  int4 za0, za1;
  int4 b0, b1, b2, b3;
  const int c0 = tid, c1 = tid + 256;

#define LOADA1(ks)                                                            \
  do {                                                                        \
    { const int kc = c0 >> 7, mp = c0 & 127;                                  \
      za0 = *(const int4*)(Zb + (size_t)(bm + (mp ^ kc)) * D_DIM +            \
                           (ks) * 32 + kc * 8); }                             \
    { const int kc = c1 >> 7, mp = c1 & 127;                                  \
      za1 = *(const int4*)(Zb + (size_t)(bm + (mp ^ kc)) * D_DIM +            \
                           (ks) * 32 + kc * 8); }                             \
  } while (0)

#define WRITEA1(buf)                                                          \
  do {                                                                        \
    AchW[(buf) * 512 + c0] = za0;                                             \
    AchW[(buf) * 512 + c1] = za1;                                             \
  } while (0)

#define LOADB1(ks)                                                            \
  do {                                                                        \
    b0 = imgI[(ks) * 1024 + tid];                                             \
    b1 = imgI[(ks) * 1024 + tid + 256];                                       \
    b2 = imgI[(ks) * 1024 + tid + 512];                                       \
    b3 = imgI[(ks) * 1024 + tid + 768];                                       \
  } while (0)

#define WRITEB1(buf)                                                          \
  do {                                                                        \
    BchW[(buf) * 1024 + tid] = b0;                                            \
    BchW[(buf) * 1024 + tid + 256] = b1;                                      \
    BchW[(buf) * 1024 + tid + 512] = b2;                                      \
    BchW[(buf) * 1024 + tid + 768] = b3;                                      \
  } while (0)

  f32x4 acc[4][4] = {};

  LOADA1(0);
  LOADB1(0);
  WRITEA1(0);
  WRITEB1(0);
  __syncthreads();

  int cur = 0;
  for (int ks = 0; ks < 12; ++ks) {
    if (ks < 11) { LOADA1(ks + 1); LOADB1(ks + 1); }
    s16x8 af[4];
#pragma unroll
    for (int fm = 0; fm < 4; ++fm) af[fm] = AchR[cur * 512 + axc[fm]];
#pragma unroll
    for (int fn = 0; fn < 4; ++fn) {
      const s16x8 bf0 = BchR[cur * 1024 + bxc[fn]];
      const s16x8 bf1 = BchR[cur * 1024 + 512 + bxc[fn]];
#pragma unroll
      for (int fm = 0; fm < 4; ++fm)
        acc[fm][fn] = __builtin_amdgcn_mfma_f32_16x16x32_bf16(af[fm], bf1, acc[fm][fn], 0, 0, 0);
#pragma unroll
      for (int fm = 0; fm < 4; ++fm)
        acc[fm][fn] = __builtin_amdgcn_mfma_f32_16x16x32_bf16(af[fm], bf0, acc[fm][fn], 0, 0, 0);
    }
    if (ks < 11) {
      WRITEA1(cur ^ 1);
      WRITEB1(cur ^ 1);
      __syncthreads();
      cur ^= 1;
    }
  }
#undef LOADA1
#undef WRITEA1
#undef LOADB1
#undef WRITEB1

#pragma unroll
  for (int fm = 0; fm < 4; ++fm)
#pragma unroll
    for (int fn = 0; fn < 4; ++fn) {
      const int row = bm + wm * 64 + fm * 16 + kcL * 4;
      const int col = bn + wn * 64 + fn * 16 + lr;
#pragma unroll
      for (int r = 0; r < 4; ++r)
        C[(size_t)(row + r) * D_DIM + col] = acc[fm][fn][r];
    }

  __syncthreads();
  double* red = (double*)shraw;
#pragma unroll
  for (int fn = 0; fn < 4; ++fn) {
    const int col = wn * 64 + fn * 16 + lr;
    const int rg = wm * 4 + kcL;
    double s = 0.0, qd = 0.0;
#pragma unroll
    for (int fm = 0; fm < 4; ++fm)
#pragma unroll
      for (int r = 0; r < 4; ++r) {
        const double v = (double)acc[fm][fn][r];
        s += v;
        qd += v * v;
      }
    red[(rg * 128 + col) * 2 + 0] = s;
    red[(rg * 128 + col) * 2 + 1] = qd;
  }
  __syncthreads();
  if (tid < 128) {
    double S = 0.0, Q = 0.0;
#pragma unroll
    for (int rg = 0; rg < 8; ++rg) {
      S += red[(rg * 128 + tid) * 2 + 0];
      Q += red[(rg * 128 + tid) * 2 + 1];
    }
    const size_t pidx = ((size_t)by * D_DIM + bn + tid) * 2;
    part[pidx + 0] = S;
    part[pidx + 1] = Q;
  }
}

// ---------------------------------------------------------------------------
// BN stats finalize (fixed order, f64). NBLK compile-time -> unrolled,
// pipelined loads (runtime trip count cost 126 us in r16).
// ---------------------------------------------------------------------------
template <int NBLK>
__global__ void bn_stats_final(const double* __restrict__ part,
                               const float* __restrict__ gamma,
                               const float* __restrict__ beta,
                               float* __restrict__ ss) {
  const int c = blockIdx.x * 64 + threadIdx.x;
  double s = 0.0, q = 0.0;
#pragma unroll 16
  for (int b = 0; b < NBLK; ++b) {
    s += part[((size_t)b * D_DIM + c) * 2 + 0];
    q += part[((size_t)b * D_DIM + c) * 2 + 1];
  }
  const double n = (double)M_ROWS;
  const double mean = s / n;
  const double var = q / n - mean * mean;
  const double rstd = 1.0 / sqrt(var + 1e-5);
  const double sc = (double)gamma[c] * rstd;
  ss[c * 2 + 0] = (float)sc;
  ss[c * 2 + 1] = (float)((double)beta[c] - mean * sc);
}

// ---------------------------------------------------------------------------
// LIF scan (64 steps, stride CH). MODE 0: BN+LIF -> u8 spikes.
// MODE 2: BN+LIF in place (f32 spikes).
// ---------------------------------------------------------------------------
template <int MODE>
__global__ __launch_bounds__(256) void lif_kernel(float* Y,
                                                  const float* __restrict__ ss,
                                                  u8* __restrict__ spikes) {
  const int c = blockIdx.x * 256 + threadIdx.x;
  const int dd = c % D_DIM;
  const float scale = ss[dd * 2 + 0];
  const float shift = ss[dd * 2 + 1];
  float v = 0.0f;
  for (int t0 = 0; t0 < T_DIM; t0 += 8) {
    float xs[8];
#pragma unroll
    for (int u = 0; u < 8; ++u) xs[u] = Y[(size_t)(t0 + u) * CH + c];
#pragma unroll
    for (int u = 0; u < 8; ++u) {
      const float xv = xs[u] * scale + shift;
      const float hh = v + (xv - v) * 0.5f;
      const float sp = (hh >= 1.0f) ? 1.0f : 0.0f;
      v = (1.0f - sp) * hh;
      if (MODE == 0)
        spikes[(size_t)(t0 + u) * CH + c] = (u8)sp;
      else
        Y[(size_t)(t0 + u) * CH + c] = sp;
    }
  }
}

// ---------------------------------------------------------------------------
// Attention + fused attn_lif, MFMA version, 4 heads per 256-thread block
// (round-10..17 passing version, unchanged).
// ---------------------------------------------------------------------------
__global__ __launch_bounds__(256) void attn_kernel(const u8* __restrict__ qs,
                                                   const u8* __restrict__ ks,
                                                   const u8* __restrict__ vs,
                                                   u16* __restrict__ z) {
  const int gid = blockIdx.x;          // (x, b, head-group)
  const int hg = (gid & 1) * 4;
  const int b = (gid >> 1) & 7;
  const int x = gid >> 4;
  const int w = threadIdx.x >> 6;
  const int h = hg + w;
  const int lane = threadIdx.x & 63;

  union Slab {
    struct { u64 qm[64]; u64 km[64]; float maskT[64]; u16 vt[48][80]; } a;  // 8960 B
    float zl[64][50];                                                       // 12800 B
  };
  __shared__ Slab sh[4];  // 51200 B
  Slab& S = sh[w];

  {
    const u8* qp = qs + ((size_t)((x * B_DIM + b) * N_DIM + lane)) * D_DIM + h * HD;
    S.a.qm[lane] = packmask48(qp);
    const size_t koff = ((size_t)((lane * B_DIM + b) * N_DIM + x)) * D_DIM + h * HD;
    S.a.km[lane] = packmask48(ks + koff);
    const u8* vp = vs + koff;
    const int4 r0 = ((const int4*)vp)[0];
    const int4 r1 = ((const int4*)vp)[1];
    const int4 r2 = ((const int4*)vp)[2];
    u32 vw[12] = {(u32)r0.x, (u32)r0.y, (u32)r0.z, (u32)r0.w,
                  (u32)r1.x, (u32)r1.y, (u32)r1.z, (u32)r1.w,
                  (u32)r2.x, (u32)r2.y, (u32)r2.z, (u32)r2.w};
#pragma unroll
    for (int ww = 0; ww < 12; ++ww) {
      const u32 u = vw[ww];
#pragma unroll
      for (int e = 0; e < 4; ++e)
        S.a.vt[ww * 4 + e][lane] = ((u >> (8 * e)) & 1u) ? (u16)0x3F80 : (u16)0;
    }
    S.a.maskT[lane] = 1.0f / (float)(1 + lane);
  }
  __syncthreads();

  const int lr = lane & 15;
  const int lg = lane >> 4;
  f32x4 acc[4][3] = {};

  for (int ksi = 0; ksi < 2; ++ksi) {
    const int j0 = lg * 8 + ksi * 32;
    s16x8 bf[3];
#pragma unroll
    for (int nf = 0; nf < 3; ++nf)
      bf[nf] = *(const s16x8*)&S.a.vt[lr + nf * 16][j0];
    s16x8 af[3][4];
#pragma unroll
    for (int mf = 0; mf < 4; ++mf) {
      const int i = lr + mf * 16;
      const u64 qi = S.a.qm[i];
      union { u32 w[4]; s16x8 v; } p1, p2, p3;
#pragma unroll
      for (int pp = 0; pp < 4; ++pp) {
        u16 aa[2], bb[2], cc[2];
#pragma unroll
        for (int e = 0; e < 2; ++e) {
          const int j = j0 + pp * 2 + e;
          const int cnt = __popcll(qi & S.a.km[j]);
          int ad = i - j;
          if (ad < 0) ad = -ad;
          const float sv = (float)cnt * S.a.maskT[ad];
          split1(sv, aa[e], bb[e], cc[e]);
        }
        p1.w[pp] = (u32)aa[0] | ((u32)aa[1] << 16);
        p2.w[pp] = (u32)bb[0] | ((u32)bb[1] << 16);
        p3.w[pp] = (u32)cc[0] | ((u32)cc[1] << 16);
      }
      af[0][mf] = p1.v;
      af[1][mf] = p2.v;
      af[2][mf] = p3.v;
    }
#pragma unroll
    for (int spi = 0; spi < 3; ++spi) {
      const int sp = 2 - spi;
#pragma unroll
      for (int nf = 0; nf < 3; ++nf)
#pragma unroll
        for (int mf = 0; mf < 4; ++mf)
          acc[mf][nf] = __builtin_amdgcn_mfma_f32_16x16x32_bf16(af[sp][mf], bf[nf],
                                                                acc[mf][nf], 0, 0, 0);
    }
  }
  __syncthreads();

  const float kScale = 0.05103103630798287f;  // 384^-0.5
#pragma unroll
  for (int mf = 0; mf < 4; ++mf)
#pragma unroll
    for (int nf = 0; nf < 3; ++nf)
#pragma unroll
      for (int r = 0; r < 4; ++r)
        S.zl[mf * 16 + lg * 4 + r][lr + nf * 16] = acc[mf][nf][r] * kScale;
  __syncthreads();

  if (lane < HD) {
    float v = 0.0f;
    for (int i0 = 0; i0 < 64; i0 += 8) {
      float zv[8];
#pragma unroll
      for (int u = 0; u < 8; ++u) zv[u] = S.zl[i0 + u][lane];
#pragma unroll
      for (int u = 0; u < 8; ++u) {
        const float hh = v + (zv[u] - v) * 0.5f;
        const u16 sp16 = (hh >= 1.0f) ? (u16)0x3F80 : (u16)0;
        v = (hh >= 1.0f) ? 0.0f : hh;
        z[((size_t)(((i0 + u) * B_DIM + b) * T_DIM + x)) * D_DIM + h * HD + lane] = sp16;
      }
    }
  }
}

// ---------------------------------------------------------------------------
extern "C" void kernel_launch(void* const* d_in, const int* in_sizes, int n_in,
                              void* d_out, int out_size, void* d_ws, size_t ws_size,
                              hipStream_t stream) {
  const float* q  = (const float*)d_in[0];
  const float* kv = (const float*)d_in[1];
  const float* Wq = (const float*)d_in[2];
  const float* gq = (const float*)d_in[3];
  const float* bq = (const float*)d_in[4];
  const float* Wk = (const float*)d_in[5];
  const float* gk = (const float*)d_in[6];
  const float* bk = (const float*)d_in[7];
  const float* Wv = (const float*)d_in[8];
  const float* gv = (const float*)d_in[9];
  const float* bv = (const float*)d_in[10];
  const float* Wp = (const float*)d_in[11];
  const float* gp = (const float*)d_in[12];
  const float* bp = (const float*)d_in[13];
  float* out = (float*)d_out;
  char* ws = (char*)d_ws;

  // workspace layout (bytes)
  float* Ybuf  = (float*)(ws + 0);                // 50,331,648 (Y); Zb aliases head
  u16*   Zb    = (u16*)(ws + 0);                  // 25,165,824 (bf16 spikes, after Y dead)
  double* part = (double*)(ws + 50331648ull);     //  1,572,864 (256 strips)
  float* ss    = (float*)(ws + 53477376ull);      //      3,072
  u8* qsb      = (u8*)(ws + 53480448ull);         // 12,582,912
  u8* ksb      = (u8*)(ws + 66063360ull);         // 12,582,912
  u8* vsb      = (u8*)(ws + 78646272ull);         // 12,582,912
  char* Wimg   = (char*)(ws + 91229184ull);       //  2,359,296 (4 x 589,824)

  const int GBLK = 768;  // 1D swizzled grid (3 ntiles x 256 m-strips of 128)

  // --- weight split images (one pass, L2-resident afterwards) ---
  prep_w<<<12, 256, 0, stream>>>(Wq, Wk, Wv, Wp, Wimg);

  // --- q branch ---
  gemm_bn2<<<GBLK, 256, 0, stream>>>(q, Wimg + 0 * (size_t)IMG_PER_W, Ybuf, part);
  bn_stats_final<256><<<6, 64, 0, stream>>>(part, gq, bq, ss);
  lif_kernel<0><<<CH / 256, 256, 0, stream>>>(Ybuf, ss, qsb);

  // --- k branch ---
  gemm_bn2<<<GBLK, 256, 0, stream>>>(kv, Wimg + 1 * (size_t)IMG_PER_W, Ybuf, part);
  bn_stats_final<256><<<6, 64, 0, stream>>>(part, gk, bk, ss);
  lif_kernel<0><<<CH / 256, 256, 0, stream>>>(Ybuf, ss, ksb);

  // --- v branch ---
  gemm_bn2<<<GBLK, 256, 0, stream>>>(kv, Wimg + 2 * (size_t)IMG_PER_W, Ybuf, part);
  bn_stats_final<256><<<6, 64, 0, stream>>>(part, gv, bv, ss);
  lif_kernel<0><<<CH / 256, 256, 0, stream>>>(Ybuf, ss, vsb);

  // --- attention + fused attn_lif -> bf16 spikes in Zb (Ybuf dead) ---
  attn_kernel<<<T_DIM * B_DIM * 2, 256, 0, stream>>>(qsb, ksb, vsb, Zb);

  // --- proj GEMM (binary A, 2 products) -> d_out, stats fused, proj_lif ---
  gemm_bn1<<<GBLK, 256, 0, stream>>>(Zb, Wimg + 3 * (size_t)IMG_PER_W, out, part);
  bn_stats_final<256><<<6, 64, 0, stream>>>(part, gp, bp, ss);
  lif_kernel<2><<<CH / 256, 256, 0, stream>>>(out, ss, (u8*)nullptr);
}

// Round 19
// 248.678 us; speedup vs baseline: 2.6104x; 1.0015x over previous
//
#include <hip/hip_runtime.h>

typedef unsigned char u8;
typedef unsigned short u16;
typedef unsigned int u32;
typedef unsigned long long u64;
typedef __attribute__((ext_vector_type(8))) short s16x8;   // 8 bf16 = 4 VGPR
typedef __attribute__((ext_vector_type(4))) float f32x4;   // MFMA acc

#define T_DIM 64
#define B_DIM 8
#define N_DIM 64
#define D_DIM 384
#define H_DIM 8
#define HD 48
#define M_ROWS 32768
#define CH 196608

// W split-image geometry: per W: [ntile 3][kstep 12][split 2][kc 4][n 128][ki 8] bf16
#define IMG_PER_KSTEP 16384            // 1024 chunks * 16B
#define IMG_PER_NTILE (12 * IMG_PER_KSTEP)
#define IMG_PER_W (3 * IMG_PER_NTILE)  // 589824 B

// ---------------------------------------------------------------------------
// Exact bf16 truncation split helpers
// ---------------------------------------------------------------------------
__device__ __forceinline__ void split8(const float* e, int4& o1, int4& o2, int4& o3) {
  u16 h1[8], h2[8], h3[8];
#pragma unroll
  for (int i = 0; i < 8; ++i) {
    const float x = e[i];
    const u32 b = __float_as_uint(x);
    h1[i] = (u16)(b >> 16);
    const float x1 = __uint_as_float(b & 0xFFFF0000u);
    const float r1 = x - x1;
    const u32 c = __float_as_uint(r1);
    h2[i] = (u16)(c >> 16);
    const float x2 = __uint_as_float(c & 0xFFFF0000u);
    const float r2 = r1 - x2;
    h3[i] = (u16)(__float_as_uint(r2) >> 16);
  }
  o1 = make_int4((int)((u32)h1[0] | ((u32)h1[1] << 16)), (int)((u32)h1[2] | ((u32)h1[3] << 16)),
                 (int)((u32)h1[4] | ((u32)h1[5] << 16)), (int)((u32)h1[6] | ((u32)h1[7] << 16)));
  o2 = make_int4((int)((u32)h2[0] | ((u32)h2[1] << 16)), (int)((u32)h2[2] | ((u32)h2[3] << 16)),
                 (int)((u32)h2[4] | ((u32)h2[5] << 16)), (int)((u32)h2[6] | ((u32)h2[7] << 16)));
  o3 = make_int4((int)((u32)h3[0] | ((u32)h3[1] << 16)), (int)((u32)h3[2] | ((u32)h3[3] << 16)),
                 (int)((u32)h3[4] | ((u32)h3[5] << 16)), (int)((u32)h3[6] | ((u32)h3[7] << 16)));
}

// 2-way split only (A-side)
__device__ __forceinline__ void split8_2(const float* e, int4& o1, int4& o2) {
  u16 h1[8], h2[8];
#pragma unroll
  for (int i = 0; i < 8; ++i) {
    const float x = e[i];
    const u32 b = __float_as_uint(x);
    h1[i] = (u16)(b >> 16);
    const float x1 = __uint_as_float(b & 0xFFFF0000u);
    const float r1 = x - x1;
    h2[i] = (u16)(__float_as_uint(r1) >> 16);
  }
  o1 = make_int4((int)((u32)h1[0] | ((u32)h1[1] << 16)), (int)((u32)h1[2] | ((u32)h1[3] << 16)),
                 (int)((u32)h1[4] | ((u32)h1[5] << 16)), (int)((u32)h1[6] | ((u32)h1[7] << 16)));
  o2 = make_int4((int)((u32)h2[0] | ((u32)h2[1] << 16)), (int)((u32)h2[2] | ((u32)h2[3] << 16)),
                 (int)((u32)h2[4] | ((u32)h2[5] << 16)), (int)((u32)h2[6] | ((u32)h2[7] << 16)));
}

__device__ __forceinline__ void split1(float xx, u16& a, u16& b2, u16& c) {
  const u32 u = __float_as_uint(xx);
  a = (u16)(u >> 16);
  const float x1 = __uint_as_float(u & 0xFFFF0000u);
  const float r1 = xx - x1;
  const u32 u2 = __float_as_uint(r1);
  b2 = (u16)(u2 >> 16);
  const float x2 = __uint_as_float(u2 & 0xFFFF0000u);
  const float r2 = r1 - x2;
  c = (u16)(__float_as_uint(r2) >> 16);
}

__device__ __forceinline__ u64 packmask48(const u8* p) {
  const int4 r0 = ((const int4*)p)[0];
  const int4 r1 = ((const int4*)p)[1];
  const int4 r2 = ((const int4*)p)[2];
  u32 wv[12] = {(u32)r0.x, (u32)r0.y, (u32)r0.z, (u32)r0.w,
                (u32)r1.x, (u32)r1.y, (u32)r1.z, (u32)r1.w,
                (u32)r2.x, (u32)r2.y, (u32)r2.z, (u32)r2.w};
  u64 bits = 0;
#pragma unroll
  for (int w = 0; w < 12; ++w) {
    const u32 u = wv[w];
    const u32 nib = (u & 1u) | ((u >> 7) & 2u) | ((u >> 14) & 4u) | ((u >> 21) & 8u);
    bits |= (u64)nib << (w * 4);
  }
  return bits;
}

// ---------------------------------------------------------------------------
// prep_w: split weight matrices into 2-split fragment-image layout (swizzled).
// ---------------------------------------------------------------------------
__global__ __launch_bounds__(256) void prep_w(const float* __restrict__ W0,
                                              const float* __restrict__ W1,
                                              const float* __restrict__ W2,
                                              const float* __restrict__ W3,
                                              char* __restrict__ img) {
  const int widx = blockIdx.x & 3;
  const int nt = blockIdx.x >> 2;
  const float* W = (widx == 0) ? W0 : (widx == 1) ? W1 : (widx == 2) ? W2 : W3;
  char* base = img + (size_t)widx * IMG_PER_W + (size_t)nt * IMG_PER_NTILE;
  const int tid = threadIdx.x;
  const int nr = tid >> 1;
  const int kh = tid & 1;
  for (int ks = 0; ks < 12; ++ks) {
    const float* src = W + (size_t)(nt * 128 + nr) * D_DIM + ks * 32 + kh * 16;
    float4 v0 = ((const float4*)src)[0];
    float4 v1 = ((const float4*)src)[1];
    float4 v2 = ((const float4*)src)[2];
    float4 v3 = ((const float4*)src)[3];
    float e[16] = {v0.x, v0.y, v0.z, v0.w, v1.x, v1.y, v1.z, v1.w,
                   v2.x, v2.y, v2.z, v2.w, v3.x, v3.y, v3.z, v3.w};
    int4* dst = (int4*)(base + (size_t)ks * IMG_PER_KSTEP);
#pragma unroll
    for (int sub = 0; sub < 2; ++sub) {
      const int kc = kh * 2 + sub;
      int4 o1, o2, o3;
      split8(e + sub * 8, o1, o2, o3);
      dst[(0 * 4 + kc) * 128 + (nr ^ kc)] = o1;
      dst[(1 * 4 + kc) * 128 + (nr ^ kc)] = o2;
    }
  }
}

// ---------------------------------------------------------------------------
// XCD-locality swizzle decode: wgid%8 == by%8 for all 3 ntile-blocks of one
// A m-strip -> same XCD, A L2-shared.
// ---------------------------------------------------------------------------
__device__ __forceinline__ void decode_wg(int wgid, int& ntx, int& by) {
  const int xcdSlot = wgid & 7;
  const int inner = wgid >> 3;
  ntx = inner % 3;
  by = (inner / 3) * 8 + xcdSlot;
}

// ---------------------------------------------------------------------------
// gemm_bn2 (qkv): 128x128 tile, 2x2 waves, single-buffered LDS, 2 barriers
// per K-step — r12/r18 proven structure. NEW (r19): split8_2 hoisted to the
// pre-barrier compute phase (register-only, identical values) so the
// serialized inter-barrier region holds only the 8 LDS writes.
// Products: (A1,B0),(A0,B1),(A0,B0).
// ---------------------------------------------------------------------------
__global__ __launch_bounds__(256) void gemm_bn2(const float* __restrict__ A,
                                                const char* __restrict__ imgW,
                                                float* __restrict__ C,
                                                double* __restrict__ part) {
  __shared__ __align__(16) char shraw[32768];   // A planes 16KB + B 16KB
  int4* AchW = (int4*)shraw;
  int4* BchW = (int4*)(shraw + 16384);
  const s16x8* AchR = (const s16x8*)shraw;
  const s16x8* BchR = (const s16x8*)(shraw + 16384);

  const int tid = threadIdx.x;
  const int lane = tid & 63;
  const int w = tid >> 6;
  const int wm = w >> 1, wn = w & 1;
  const int lr = lane & 15;
  const int kcL = lane >> 4;

  int ntx, by;
  decode_wg(blockIdx.x, ntx, by);
  const int bn = ntx * 128;
  const int bm = by * 128;

  const int4* imgI = (const int4*)(imgW + (size_t)ntx * IMG_PER_NTILE);

  int axc[4], bxc[4];
#pragma unroll
  for (int f = 0; f < 4; ++f) {
    axc[f] = kcL * 128 + ((wm * 64 + f * 16 + lr) ^ kcL);
    bxc[f] = kcL * 128 + ((wn * 64 + f * 16 + lr) ^ kcL);
  }

  float4 a0, a1, a2, a3;
  int4 b0, b1, b2, b3;
  int4 oA0a, oA0b, oA1a, oA1b;   // pre-split A halves (held across barrier)
  const int arow = tid >> 1, akh = tid & 1;

#define LOADA(ks)                                                             \
  do {                                                                        \
    const float* ap = A + (size_t)(bm + arow) * D_DIM + (ks) * 32 + akh * 16; \
    a0 = ((const float4*)ap)[0]; a1 = ((const float4*)ap)[1];                 \
    a2 = ((const float4*)ap)[2]; a3 = ((const float4*)ap)[3];                 \
  } while (0)

#define LOADB(ks)                                                             \
  do {                                                                        \
    b0 = imgI[(ks) * 1024 + tid];                                             \
    b1 = imgI[(ks) * 1024 + tid + 256];                                       \
    b2 = imgI[(ks) * 1024 + tid + 512];                                       \
    b3 = imgI[(ks) * 1024 + tid + 768];                                       \
  } while (0)

// register-only: identical values/order as before, just computed pre-barrier
#define SPLITPRE()                                                            \
  do {                                                                        \
    float e0[8] = {a0.x, a0.y, a0.z, a0.w, a1.x, a1.y, a1.z, a1.w};           \
    float e1[8] = {a2.x, a2.y, a2.z, a2.w, a3.x, a3.y, a3.z, a3.w};           \
    split8_2(e0, oA0a, oA0b);                                                 \
    split8_2(e1, oA1a, oA1b);                                                 \
  } while (0)

#define WRITES()                                                              \
  do {                                                                        \
    { const int kc = akh * 2;                                                 \
      AchW[0 * 512 + kc * 128 + (arow ^ kc)] = oA0a;                          \
      AchW[1 * 512 + kc * 128 + (arow ^ kc)] = oA0b; }                        \
    { const int kc = akh * 2 + 1;                                             \
      AchW[0 * 512 + kc * 128 + (arow ^ kc)] = oA1a;                          \
      AchW[1 * 512 + kc * 128 + (arow ^ kc)] = oA1b; }                        \
    BchW[tid] = b0; BchW[tid + 256] = b1;                                     \
    BchW[tid + 512] = b2; BchW[tid + 768] = b3;                               \
  } while (0)

  f32x4 acc[4][4] = {};

  LOADA(0); LOADB(0);
  SPLITPRE();
  WRITES();
  __syncthreads();

  for (int ks = 0; ks < 12; ++ks) {
    if (ks < 11) { LOADA(ks + 1); LOADB(ks + 1); }
    s16x8 af[2][4];
#pragma unroll
    for (int s = 0; s < 2; ++s)
#pragma unroll
      for (int fm = 0; fm < 4; ++fm) af[s][fm] = AchR[s * 512 + axc[fm]];
#pragma unroll
    for (int fn = 0; fn < 4; ++fn) {
      const s16x8 bf0 = BchR[bxc[fn]];
      const s16x8 bf1 = BchR[512 + bxc[fn]];
#pragma unroll
      for (int fm = 0; fm < 4; ++fm)
        acc[fm][fn] = __builtin_amdgcn_mfma_f32_16x16x32_bf16(af[1][fm], bf0, acc[fm][fn], 0, 0, 0);
#pragma unroll
      for (int fm = 0; fm < 4; ++fm)
        acc[fm][fn] = __builtin_amdgcn_mfma_f32_16x16x32_bf16(af[0][fm], bf1, acc[fm][fn], 0, 0, 0);
#pragma unroll
      for (int fm = 0; fm < 4; ++fm)
        acc[fm][fn] = __builtin_amdgcn_mfma_f32_16x16x32_bf16(af[0][fm], bf0, acc[fm][fn], 0, 0, 0);
    }
    if (ks < 11) SPLITPRE();   // VALU + vmcnt wait hidden in compute phase
    __syncthreads();
    if (ks < 11) {
      WRITES();                 // only LDS writes between the barriers
      __syncthreads();
    }
  }
#undef LOADA
#undef LOADB
#undef SPLITPRE
#undef WRITES

#pragma unroll
  for (int fm = 0; fm < 4; ++fm)
#pragma unroll
    for (int fn = 0; fn < 4; ++fn) {
      const int row = bm + wm * 64 + fm * 16 + kcL * 4;
      const int col = bn + wn * 64 + fn * 16 + lr;
#pragma unroll
      for (int r = 0; r < 4; ++r)
        C[(size_t)(row + r) * D_DIM + col] = acc[fm][fn][r];
    }

  __syncthreads();
  double* red = (double*)shraw;
#pragma unroll
  for (int fn = 0; fn < 4; ++fn) {
    const int col = wn * 64 + fn * 16 + lr;
    const int rg = wm * 4 + kcL;
    double s = 0.0, qd = 0.0;
#pragma unroll
    for (int fm = 0; fm < 4; ++fm)
#pragma unroll
      for (int r = 0; r < 4; ++r) {
        const double v = (double)acc[fm][fn][r];
        s += v;
        qd += v * v;
      }
    red[(rg * 128 + col) * 2 + 0] = s;
    red[(rg * 128 + col) * 2 + 1] = qd;
  }
  __syncthreads();
  if (tid < 128) {
    double S = 0.0, Q = 0.0;
#pragma unroll
    for (int rg = 0; rg < 8; ++rg) {
      S += red[(rg * 128 + tid) * 2 + 0];
      Q += red[(rg * 128 + tid) * 2 + 1];
    }
    const size_t pidx = ((size_t)by * D_DIM + bn + tid) * 2;
    part[pidx + 0] = S;
    part[pidx + 1] = Q;
  }
}

// ---------------------------------------------------------------------------
// gemm_bn1 (proj) — round-13 proven version: A bf16 spikes + B both
// double-buffered in LDS (48 KB), ONE barrier per K-step. 2 products.
// ---------------------------------------------------------------------------
__global__ __launch_bounds__(256) void gemm_bn1(const u16* __restrict__ Zb,
                                                const char* __restrict__ imgW,
                                                float* __restrict__ C,
                                                double* __restrict__ part) {
  __shared__ __align__(16) char shraw[49152];   // B[2][16384] @0, A[2][8192] @32768
  int4* BchW = (int4*)shraw;
  const s16x8* BchR = (const s16x8*)shraw;
  int4* AchW = (int4*)shraw + 2048;
  const s16x8* AchR = (const s16x8*)shraw + 2048;

  const int tid = threadIdx.x;
  const int lane = tid & 63;
  const int w = tid >> 6;
  const int wm = w >> 1, wn = w & 1;
  const int lr = lane & 15;
  const int kcL = lane >> 4;

  int ntx, by;
  decode_wg(blockIdx.x, ntx, by);
  const int bn = ntx * 128;
  const int bm = by * 128;

  const int4* imgI = (const int4*)(imgW + (size_t)ntx * IMG_PER_NTILE);

  int axc[4], bxc[4];
#pragma unroll
  for (int f = 0; f < 4; ++f) {
    axc[f] = kcL * 128 + ((wm * 64 + f * 16 + lr) ^ kcL);
    bxc[f] = kcL * 128 + ((wn * 64 + f * 16 + lr) ^ kcL);
  }

  int4 za0, za1;
  int4 b0, b1, b2, b3;
  const int c0 = tid, c1 = tid + 256;

#define LOADA1(ks)                                                            \
  do {                                                                        \
    { const int kc = c0 >> 7, mp = c0 & 127;                                  \
      za0 = *(const int4*)(Zb + (size_t)(bm + (mp ^ kc)) * D_DIM +            \
                           (ks) * 32 + kc * 8); }                             \
    { const int kc = c1 >> 7, mp = c1 & 127;                                  \
      za1 = *(const int4*)(Zb + (size_t)(bm + (mp ^ kc)) * D_DIM +            \
                           (ks) * 32 + kc * 8); }                             \
  } while (0)

#define WRITEA1(buf)                                                          \
  do {                                                                        \
    AchW[(buf) * 512 + c0] = za0;                                             \
    AchW[(buf) * 512 + c1] = za1;                                             \
  } while (0)

#define LOADB1(ks)                                                            \
  do {                                                                        \
    b0 = imgI[(ks) * 1024 + tid];                                             \
    b1 = imgI[(ks) * 1024 + tid + 256];                                       \
    b2 = imgI[(ks) * 1024 + tid + 512];                                       \
    b3 = imgI[(ks) * 1024 + tid + 768];                                       \
  } while (0)

#define WRITEB1(buf)                                                          \
  do {                                                                        \
    BchW[(buf) * 1024 + tid] = b0;                                            \
    BchW[(buf) * 1024 + tid + 256] = b1;                                      \
    BchW[(buf) * 1024 + tid + 512] = b2;                                      \
    BchW[(buf) * 1024 + tid + 768] = b3;                                      \
  } while (0)

  f32x4 acc[4][4] = {};

  LOADA1(0);
  LOADB1(0);
  WRITEA1(0);
  WRITEB1(0);
  __syncthreads();

  int cur = 0;
  for (int ks = 0; ks < 12; ++ks) {
    if (ks < 11) { LOADA1(ks + 1); LOADB1(ks + 1); }
    s16x8 af[4];
#pragma unroll
    for (int fm = 0; fm < 4; ++fm) af[fm] = AchR[cur * 512 + axc[fm]];
#pragma unroll
    for (int fn = 0; fn < 4; ++fn) {
      const s16x8 bf0 = BchR[cur * 1024 + bxc[fn]];
      const s16x8 bf1 = BchR[cur * 1024 + 512 + bxc[fn]];
#pragma unroll
      for (int fm = 0; fm < 4; ++fm)
        acc[fm][fn] = __builtin_amdgcn_mfma_f32_16x16x32_bf16(af[fm], bf1, acc[fm][fn], 0, 0, 0);
#pragma unroll
      for (int fm = 0; fm < 4; ++fm)
        acc[fm][fn] = __builtin_amdgcn_mfma_f32_16x16x32_bf16(af[fm], bf0, acc[fm][fn], 0, 0, 0);
    }
    if (ks < 11) {
      WRITEA1(cur ^ 1);
      WRITEB1(cur ^ 1);
      __syncthreads();
      cur ^= 1;
    }
  }
#undef LOADA1
#undef WRITEA1
#undef LOADB1
#undef WRITEB1

#pragma unroll
  for (int fm = 0; fm < 4; ++fm)
#pragma unroll
    for (int fn = 0; fn < 4; ++fn) {
      const int row = bm + wm * 64 + fm * 16 + kcL * 4;
      const int col = bn + wn * 64 + fn * 16 + lr;
#pragma unroll
      for (int r = 0; r < 4; ++r)
        C[(size_t)(row + r) * D_DIM + col] = acc[fm][fn][r];
    }

  __syncthreads();
  double* red = (double*)shraw;
#pragma unroll
  for (int fn = 0; fn < 4; ++fn) {
    const int col = wn * 64 + fn * 16 + lr;
    const int rg = wm * 4 + kcL;
    double s = 0.0, qd = 0.0;
#pragma unroll
    for (int fm = 0; fm < 4; ++fm)
#pragma unroll
      for (int r = 0; r < 4; ++r) {
        const double v = (double)acc[fm][fn][r];
        s += v;
        qd += v * v;
      }
    red[(rg * 128 + col) * 2 + 0] = s;
    red[(rg * 128 + col) * 2 + 1] = qd;
  }
  __syncthreads();
  if (tid < 128) {
    double S = 0.0, Q = 0.0;
#pragma unroll
    for (int rg = 0; rg < 8; ++rg) {
      S += red[(rg * 128 + tid) * 2 + 0];
      Q += red[(rg * 128 + tid) * 2 + 1];
    }
    const size_t pidx = ((size_t)by * D_DIM + bn + tid) * 2;
    part[pidx + 0] = S;
    part[pidx + 1] = Q;
  }
}

// ---------------------------------------------------------------------------
// BN stats finalize (fixed order, f64). NBLK compile-time -> unrolled.
// ---------------------------------------------------------------------------
template <int NBLK>
__global__ void bn_stats_final(const double* __restrict__ part,
                               const float* __restrict__ gamma,
                               const float* __restrict__ beta,
                               float* __restrict__ ss) {
  const int c = blockIdx.x * 64 + threadIdx.x;
  double s = 0.0, q = 0.0;
#pragma unroll 16
  for (int b = 0; b < NBLK; ++b) {
    s += part[((size_t)b * D_DIM + c) * 2 + 0];
    q += part[((size_t)b * D_DIM + c) * 2 + 1];
  }
  const double n = (double)M_ROWS;
  const double mean = s / n;
  const double var = q / n - mean * mean;
  const double rstd = 1.0 / sqrt(var + 1e-5);
  const double sc = (double)gamma[c] * rstd;
  ss[c * 2 + 0] = (float)sc;
  ss[c * 2 + 1] = (float)((double)beta[c] - mean * sc);
}

// ---------------------------------------------------------------------------
// LIF scan (64 steps, stride CH). MODE 0: BN+LIF -> u8 spikes.
// MODE 2: BN+LIF in place (f32 spikes).
// ---------------------------------------------------------------------------
template <int MODE>
__global__ __launch_bounds__(256) void lif_kernel(float* Y,
                                                  const float* __restrict__ ss,
                                                  u8* __restrict__ spikes) {
  const int c = blockIdx.x * 256 + threadIdx.x;
  const int dd = c % D_DIM;
  const float scale = ss[dd * 2 + 0];
  const float shift = ss[dd * 2 + 1];
  float v = 0.0f;
  for (int t0 = 0; t0 < T_DIM; t0 += 8) {
    float xs[8];
#pragma unroll
    for (int u = 0; u < 8; ++u) xs[u] = Y[(size_t)(t0 + u) * CH + c];
#pragma unroll
    for (int u = 0; u < 8; ++u) {
      const float xv = xs[u] * scale + shift;
      const float hh = v + (xv - v) * 0.5f;
      const float sp = (hh >= 1.0f) ? 1.0f : 0.0f;
      v = (1.0f - sp) * hh;
      if (MODE == 0)
        spikes[(size_t)(t0 + u) * CH + c] = (u8)sp;
      else
        Y[(size_t)(t0 + u) * CH + c] = sp;
    }
  }
}

// ---------------------------------------------------------------------------
// Attention + fused attn_lif, MFMA version, 4 heads per 256-thread block
// (round-10..18 passing version, unchanged).
// ---------------------------------------------------------------------------
__global__ __launch_bounds__(256) void attn_kernel(const u8* __restrict__ qs,
                                                   const u8* __restrict__ ks,
                                                   const u8* __restrict__ vs,
                                                   u16* __restrict__ z) {
  const int gid = blockIdx.x;          // (x, b, head-group)
  const int hg = (gid & 1) * 4;
  const int b = (gid >> 1) & 7;
  const int x = gid >> 4;
  const int w = threadIdx.x >> 6;
  const int h = hg + w;
  const int lane = threadIdx.x & 63;

  union Slab {
    struct { u64 qm[64]; u64 km[64]; float maskT[64]; u16 vt[48][80]; } a;  // 8960 B
    float zl[64][50];                                                       // 12800 B
  };
  __shared__ Slab sh[4];  // 51200 B
  Slab& S = sh[w];

  {
    const u8* qp = qs + ((size_t)((x * B_DIM + b) * N_DIM + lane)) * D_DIM + h * HD;
    S.a.qm[lane] = packmask48(qp);
    const size_t koff = ((size_t)((lane * B_DIM + b) * N_DIM + x)) * D_DIM + h * HD;
    S.a.km[lane] = packmask48(ks + koff);
    const u8* vp = vs + koff;
    const int4 r0 = ((const int4*)vp)[0];
    const int4 r1 = ((const int4*)vp)[1];
    const int4 r2 = ((const int4*)vp)[2];
    u32 vw[12] = {(u32)r0.x, (u32)r0.y, (u32)r0.z, (u32)r0.w,
                  (u32)r1.x, (u32)r1.y, (u32)r1.z, (u32)r1.w,
                  (u32)r2.x, (u32)r2.y, (u32)r2.z, (u32)r2.w};
#pragma unroll
    for (int ww = 0; ww < 12; ++ww) {
      const u32 u = vw[ww];
#pragma unroll
      for (int e = 0; e < 4; ++e)
        S.a.vt[ww * 4 + e][lane] = ((u >> (8 * e)) & 1u) ? (u16)0x3F80 : (u16)0;
    }
    S.a.maskT[lane] = 1.0f / (float)(1 + lane);
  }
  __syncthreads();

  const int lr = lane & 15;
  const int lg = lane >> 4;
  f32x4 acc[4][3] = {};

  for (int ksi = 0; ksi < 2; ++ksi) {
    const int j0 = lg * 8 + ksi * 32;
    s16x8 bf[3];
#pragma unroll
    for (int nf = 0; nf < 3; ++nf)
      bf[nf] = *(const s16x8*)&S.a.vt[lr + nf * 16][j0];
    s16x8 af[3][4];
#pragma unroll
    for (int mf = 0; mf < 4; ++mf) {
      const int i = lr + mf * 16;
      const u64 qi = S.a.qm[i];
      union { u32 w[4]; s16x8 v; } p1, p2, p3;
#pragma unroll
      for (int pp = 0; pp < 4; ++pp) {
        u16 aa[2], bb[2], cc[2];
#pragma unroll
        for (int e = 0; e < 2; ++e) {
          const int j = j0 + pp * 2 + e;
          const int cnt = __popcll(qi & S.a.km[j]);
          int ad = i - j;
          if (ad < 0) ad = -ad;
          const float sv = (float)cnt * S.a.maskT[ad];
          split1(sv, aa[e], bb[e], cc[e]);
        }
        p1.w[pp] = (u32)aa[0] | ((u32)aa[1] << 16);
        p2.w[pp] = (u32)bb[0] | ((u32)bb[1] << 16);
        p3.w[pp] = (u32)cc[0] | ((u32)cc[1] << 16);
      }
      af[0][mf] = p1.v;
      af[1][mf] = p2.v;
      af[2][mf] = p3.v;
    }
#pragma unroll
    for (int spi = 0; spi < 3; ++spi) {
      const int sp = 2 - spi;
#pragma unroll
      for (int nf = 0; nf < 3; ++nf)
#pragma unroll
        for (int mf = 0; mf < 4; ++mf)
          acc[mf][nf] = __builtin_amdgcn_mfma_f32_16x16x32_bf16(af[sp][mf], bf[nf],
                                                                acc[mf][nf], 0, 0, 0);
    }
  }
  __syncthreads();

  const float kScale = 0.05103103630798287f;  // 384^-0.5
#pragma unroll
  for (int mf = 0; mf < 4; ++mf)
#pragma unroll
    for (int nf = 0; nf < 3; ++nf)
#pragma unroll
      for (int r = 0; r < 4; ++r)
        S.zl[mf * 16 + lg * 4 + r][lr + nf * 16] = acc[mf][nf][r] * kScale;
  __syncthreads();

  if (lane < HD) {
    float v = 0.0f;
    for (int i0 = 0; i0 < 64; i0 += 8) {
      float zv[8];
#pragma unroll
      for (int u = 0; u < 8; ++u) zv[u] = S.zl[i0 + u][lane];
#pragma unroll
      for (int u = 0; u < 8; ++u) {
        const float hh = v + (zv[u] - v) * 0.5f;
        const u16 sp16 = (hh >= 1.0f) ? (u16)0x3F80 : (u16)0;
        v = (hh >= 1.0f) ? 0.0f : hh;
        z[((size_t)(((i0 + u) * B_DIM + b) * T_DIM + x)) * D_DIM + h * HD + lane] = sp16;
      }
    }
  }
}

// ---------------------------------------------------------------------------
extern "C" void kernel_launch(void* const* d_in, const int* in_sizes, int n_in,
                              void* d_out, int out_size, void* d_ws, size_t ws_size,
                              hipStream_t stream) {
  const float* q  = (const float*)d_in[0];
  const float* kv = (const float*)d_in[1];
  const float* Wq = (const float*)d_in[2];
  const float* gq = (const float*)d_in[3];
  const float* bq = (const float*)d_in[4];
  const float* Wk = (const float*)d_in[5];
  const float* gk = (const float*)d_in[6];
  const float* bk = (const float*)d_in[7];
  const float* Wv = (const float*)d_in[8];
  const float* gv = (const float*)d_in[9];
  const float* bv = (const float*)d_in[10];
  const float* Wp = (const float*)d_in[11];
  const float* gp = (const float*)d_in[12];
  const float* bp = (const float*)d_in[13];
  float* out = (float*)d_out;
  char* ws = (char*)d_ws;

  // workspace layout (bytes)
  float* Ybuf  = (float*)(ws + 0);                // 50,331,648 (Y); Zb aliases head
  u16*   Zb    = (u16*)(ws + 0);                  // 25,165,824 (bf16 spikes, after Y dead)
  double* part = (double*)(ws + 50331648ull);     //  1,572,864 (256 strips)
  float* ss    = (float*)(ws + 53477376ull);      //      3,072
  u8* qsb      = (u8*)(ws + 53480448ull);         // 12,582,912
  u8* ksb      = (u8*)(ws + 66063360ull);         // 12,582,912
  u8* vsb      = (u8*)(ws + 78646272ull);         // 12,582,912
  char* Wimg   = (char*)(ws + 91229184ull);       //  2,359,296 (4 x 589,824)

  const int GBLK = 768;  // 1D swizzled grid (3 ntiles x 256 m-strips of 128)

  // --- weight split images (one pass, L2-resident afterwards) ---
  prep_w<<<12, 256, 0, stream>>>(Wq, Wk, Wv, Wp, Wimg);

  // --- q branch ---
  gemm_bn2<<<GBLK, 256, 0, stream>>>(q, Wimg + 0 * (size_t)IMG_PER_W, Ybuf, part);
  bn_stats_final<256><<<6, 64, 0, stream>>>(part, gq, bq, ss);
  lif_kernel<0><<<CH / 256, 256, 0, stream>>>(Ybuf, ss, qsb);

  // --- k branch ---
  gemm_bn2<<<GBLK, 256, 0, stream>>>(kv, Wimg + 1 * (size_t)IMG_PER_W, Ybuf, part);
  bn_stats_final<256><<<6, 64, 0, stream>>>(part, gk, bk, ss);
  lif_kernel<0><<<CH / 256, 256, 0, stream>>>(Ybuf, ss, ksb);

  // --- v branch ---
  gemm_bn2<<<GBLK, 256, 0, stream>>>(kv, Wimg + 2 * (size_t)IMG_PER_W, Ybuf, part);
  bn_stats_final<256><<<6, 64, 0, stream>>>(part, gv, bv, ss);
  lif_kernel<0><<<CH / 256, 256, 0, stream>>>(Ybuf, ss, vsb);

  // --- attention + fused attn_lif -> bf16 spikes in Zb (Ybuf dead) ---
  attn_kernel<<<T_DIM * B_DIM * 2, 256, 0, stream>>>(qsb, ksb, vsb, Zb);

  // --- proj GEMM (binary A, 2 products) -> d_out, stats fused, proj_lif ---
  gemm_bn1<<<GBLK, 256, 0, stream>>>(Zb, Wimg + 3 * (size_t)IMG_PER_W, out, part);
  bn_stats_final<256><<<6, 64, 0, stream>>>(part, gp, bp, ss);
  lif_kernel<2><<<CH / 256, 256, 0, stream>>>(out, ss, (u8*)nullptr);
}